// Round 7
// baseline (1813.349 us; speedup 1.0000x reference)
//
#include <hip/hip_runtime.h>
#include <math.h>

// B=4, N=1024, C=768, H=12, D=64
// ws (floats): q[3145728] k[3145728] qpk kpk vpk (u32 views) qgrh kgrh (ushort) qn4 kn4
// attno aliases q (q f32 dead after qr/row_norms).

typedef __attribute__((ext_vector_type(8))) short short8;
typedef __attribute__((ext_vector_type(4))) float f32x4;

__device__ __forceinline__ unsigned bf16r(float x) {
    unsigned u = __float_as_uint(x);
    return (u + 0x7FFFu + ((u >> 16) & 1u)) >> 16;
}
__device__ __forceinline__ unsigned packhl(float x) {
    unsigned u = __float_as_uint(x);
    unsigned hi = (u + 0x7FFFu + ((u >> 16) & 1u)) & 0xFFFF0000u;
    float lo = x - __uint_as_float(hi);
    unsigned ul = __float_as_uint(lo);
    unsigned l16 = (ul + 0x7FFFu + ((ul >> 16) & 1u)) >> 16;
    return hi | (l16 & 0xFFFFu);
}
union U4S8 { uint4 u; short8 s; };
__device__ __forceinline__ short8 mk_hi(uint4 a, uint4 b) {
    U4S8 r;
    r.u.x = __builtin_amdgcn_perm(a.y, a.x, 0x07060302);
    r.u.y = __builtin_amdgcn_perm(a.w, a.z, 0x07060302);
    r.u.z = __builtin_amdgcn_perm(b.y, b.x, 0x07060302);
    r.u.w = __builtin_amdgcn_perm(b.w, b.z, 0x07060302);
    return r.s;
}
__device__ __forceinline__ short8 mk_lo(uint4 a, uint4 b) {
    U4S8 r;
    r.u.x = __builtin_amdgcn_perm(a.y, a.x, 0x05040100);
    r.u.y = __builtin_amdgcn_perm(a.w, a.z, 0x05040100);
    r.u.z = __builtin_amdgcn_perm(b.y, b.x, 0x05040100);
    r.u.w = __builtin_amdgcn_perm(b.w, b.z, 0x05040100);
    return r.s;
}
__device__ __forceinline__ uint4 ld4v(const unsigned* vp, int mbase, int d) {
    uint4 r;
    r.x = vp[(size_t)(mbase + 0) * 64 + d];
    r.y = vp[(size_t)(mbase + 1) * 64 + d];
    r.z = vp[(size_t)(mbase + 2) * 64 + d];
    r.w = vp[(size_t)(mbase + 3) * 64 + d];
    return r;
}
#define MFMA(a,b,c) __builtin_amdgcn_mfma_f32_16x16x32_bf16(a, b, c, 0, 0, 0)

// ---------------- K1: qkv GEMM + scatter (f32 + packed hi/lo bf16) ----------------
__global__ __launch_bounds__(256) void qkv_gemm(
    const float* __restrict__ x, const float* __restrict__ w, const float* __restrict__ bias,
    float* __restrict__ q, float* __restrict__ k,
    unsigned* __restrict__ qpk, unsigned* __restrict__ kpk, unsigned* __restrict__ vpk)
{
    __shared__ float As[16][68];
    __shared__ float Ws[16][68];
    const int tid = threadIdx.x;
    const int m0 = blockIdx.x * 64;
    const int c0 = blockIdx.y * 64;
    const int ty = tid >> 4, tx = tid & 15;
    const int lm = tid >> 2;
    const int lk = (tid & 3) * 4;
    float acc[4][4];
#pragma unroll
    for (int i = 0; i < 4; i++)
#pragma unroll
        for (int j = 0; j < 4; j++) acc[i][j] = 0.f;

    for (int kk0 = 0; kk0 < 768; kk0 += 16) {
        float4 av = *(const float4*)&x[(m0 + lm) * 768 + kk0 + lk];
        float4 wv = *(const float4*)&w[(c0 + lm) * 768 + kk0 + lk];
        __syncthreads();
        As[lk + 0][lm] = av.x; As[lk + 1][lm] = av.y; As[lk + 2][lm] = av.z; As[lk + 3][lm] = av.w;
        Ws[lk + 0][lm] = wv.x; Ws[lk + 1][lm] = wv.y; Ws[lk + 2][lm] = wv.z; Ws[lk + 3][lm] = wv.w;
        __syncthreads();
#pragma unroll
        for (int kk = 0; kk < 16; kk++) {
            float4 a  = *(const float4*)&As[kk][ty * 4];
            float4 bv = *(const float4*)&Ws[kk][tx * 4];
            acc[0][0] += a.x * bv.x; acc[0][1] += a.x * bv.y; acc[0][2] += a.x * bv.z; acc[0][3] += a.x * bv.w;
            acc[1][0] += a.y * bv.x; acc[1][1] += a.y * bv.y; acc[1][2] += a.y * bv.z; acc[1][3] += a.y * bv.w;
            acc[2][0] += a.z * bv.x; acc[2][1] += a.z * bv.y; acc[2][2] += a.z * bv.z; acc[2][3] += a.z * bv.w;
            acc[3][0] += a.w * bv.x; acc[3][1] += a.w * bv.y; acc[3][2] += a.w * bv.z; acc[3][3] += a.w * bv.w;
        }
    }
#pragma unroll
    for (int i = 0; i < 4; i++) {
        int row = m0 + ty * 4 + i;
        int bb = row >> 10, n = row & 1023;
#pragma unroll
        for (int j = 0; j < 4; j++) {
            int col = c0 + tx * 4 + j;
            float val = acc[i][j] + bias[col];
            int s = (col >= 1536) ? 2 : ((col >= 768) ? 1 : 0);
            int hc = col - s * 768;
            size_t idx = ((size_t)(bb * 12 + (hc >> 6)) << 16) + ((size_t)n << 6) + (hc & 63);
            if (s == 0)      { q[idx] = val; qpk[idx] = packhl(val); }
            else if (s == 1) { k[idx] = val; kpk[idx] = packhl(val); }
            else             { vpk[idx] = packhl(val); }
        }
    }
}

// ---------------- K1b: squared row norms (qn2^2, kn2^2) ----------------
__global__ __launch_bounds__(256) void row_norms(
    const float* __restrict__ q, const float* __restrict__ k,
    float* __restrict__ qn4, float* __restrict__ kn4)
{
    int wid = blockIdx.x * 4 + (threadIdx.x >> 6);
    int lane = threadIdx.x & 63;
    const float* src; float* dst; int r;
    if (wid < 49152) { src = q; dst = qn4; r = wid; }
    else             { src = k; dst = kn4; r = wid - 49152; }
    float xv = src[(size_t)r * 64 + lane];
    float s = xv * xv;
#pragma unroll
    for (int m = 1; m < 64; m <<= 1) s += __shfl_xor(s, m, 64);
    if (lane == 0) dst[r] = s * s;
}

// ---------------- K2: Householder QR (LAPACK signs), bf16 output ----------------
__global__ __launch_bounds__(1024) void qr_kernel(
    const float* __restrict__ q, const float* __restrict__ k,
    unsigned short* __restrict__ qgrh, unsigned short* __restrict__ kgrh)
{
    const int id = blockIdx.x;
    const float* src = (id & 1) ? k : q;
    unsigned short* dst = (id & 1) ? kgrh : qgrh;
    const int bh = id >> 1;
    src += (size_t)bh << 16;
    dst += (size_t)bh << 16;
    const int lane = threadIdx.x & 63;
    const int w = threadIdx.x >> 6;
    __shared__ float vbuf[1024];
    __shared__ float taub[64];

    float a[4][16];
#pragma unroll
    for (int c = 0; c < 4; c++)
#pragma unroll
        for (int i = 0; i < 16; i++)
            a[c][i] = src[(i * 64 + lane) * 64 + 4 * w + c];

    for (int d = 0; d < 64; d++) {
        const int wd = d >> 2, cd = d & 3;
        if (w == wd) {
#pragma unroll
            for (int c = 0; c < 4; c++) if (c == cd) {
                float part = 0.f;
#pragma unroll
                for (int i = 0; i < 16; i++) {
                    int r = i * 64 + lane; float xx = a[c][i];
                    part += (r >= d) ? xx * xx : 0.f;
                }
#pragma unroll
                for (int m = 1; m < 64; m <<= 1) part += __shfl_xor(part, m, 64);
                float sigma = part;
                float xd = __shfl(a[c][0], d, 64);
                float nrm = sqrtf(sigma);
                float beta = (xd >= 0.f) ? -nrm : nrm;
                float vd = xd - beta;
                float vtv = (sigma - xd * xd) + vd * vd;
                float tau2 = (vtv > 0.f) ? 2.f / vtv : 0.f;
                if (lane == d) a[c][0] = vd;
#pragma unroll
                for (int i = 0; i < 16; i++) {
                    int r = i * 64 + lane;
                    vbuf[r] = (r < d) ? 0.f : a[c][i];
                }
                if (lane == 0) taub[d] = tau2;
            }
        }
        __syncthreads();
        float t2 = taub[d];
#pragma unroll
        for (int c = 0; c < 4; c++) {
            int j = 4 * w + c;
            if (j > d) {
                float part = 0.f;
#pragma unroll
                for (int i = 0; i < 16; i++) part += vbuf[i * 64 + lane] * a[c][i];
#pragma unroll
                for (int m = 1; m < 64; m <<= 1) part += __shfl_xor(part, m, 64);
                float sv = t2 * part;
#pragma unroll
                for (int i = 0; i < 16; i++) a[c][i] -= sv * vbuf[i * 64 + lane];
            }
        }
        __syncthreads();
    }

    float qr[4][16];
#pragma unroll
    for (int c = 0; c < 4; c++)
#pragma unroll
        for (int i = 0; i < 16; i++) {
            int r = i * 64 + lane;
            qr[c][i] = (r == 4 * w + c) ? 1.f : 0.f;
        }
    for (int d = 63; d >= 0; d--) {
        const int wd = d >> 2, cd = d & 3;
        if (w == wd) {
#pragma unroll
            for (int c = 0; c < 4; c++) if (c == cd) {
#pragma unroll
                for (int i = 0; i < 16; i++) {
                    int r = i * 64 + lane;
                    vbuf[r] = (r < d) ? 0.f : a[c][i];
                }
            }
        }
        __syncthreads();
        float t2 = taub[d];
#pragma unroll
        for (int c = 0; c < 4; c++) {
            int j = 4 * w + c;
            if (j >= d) {
                float part = 0.f;
#pragma unroll
                for (int i = 0; i < 16; i++) part += vbuf[i * 64 + lane] * qr[c][i];
#pragma unroll
                for (int m = 1; m < 64; m <<= 1) part += __shfl_xor(part, m, 64);
                float sv = t2 * part;
#pragma unroll
                for (int i = 0; i < 16; i++) qr[c][i] -= sv * vbuf[i * 64 + lane];
            }
        }
        __syncthreads();
    }
#pragma unroll
    for (int c = 0; c < 4; c++)
#pragma unroll
        for (int i = 0; i < 16; i++)
            dst[(i * 64 + lane) * 64 + 4 * w + c] = (unsigned short)bf16r(qr[c][i]);
}

// ---------------- K3: fused MFMA scores -> conv -> BN -> online softmax -> PV ----------------
// o-SPLIT: grid.z=2, each block owns 6 of the 12 output channels (y 24 regs, acc 24 regs).
// No v-prefetch regs, no cross-m0 k-prefetch, per-ks fragment rebuild: peak ~125 VGPR.
#define SM_BYTES 159360

#define EACH_O6(F) F(0) F(1) F(2) F(3) F(4) F(5)

#define DECL_Y(o) float y##o##_0 = 0.f, y##o##_1 = 0.f, y##o##_2 = 0.f, y##o##_3 = 0.f;
#define DECL_A(o) f32x4 acc##o = (f32x4){0.f, 0.f, 0.f, 0.f};

#define LOADC(o) const float cA##o = cwS_s[(obase + o) * 36 + h], \
                             cB##o = cwS_s[(obase + o) * 36 + 12 + h], \
                             cC##o = cwS_s[(obase + o) * 36 + 24 + h];

#define CONV1(o,r) y##o##_##r = fmaf(cA##o, att, fmaf(cB##o, rie, fmaf(cC##o, gra, y##o##_##r)));
#define CONVROW(r) CONV1(0,r) CONV1(1,r) CONV1(2,r) CONV1(3,r) CONV1(4,r) CONV1(5,r)
#define SCORE_R(r) { \
    float qk = s1[r], gr = s2[r]; \
    float qn4v = qn4s[h * 16 + g * 4 + r]; \
    float att = qk * scale; \
    float d2 = qn4v + kn4v - 2.f * qk * qk; \
    float rie = -sqrtf(fmaxf(d2, 0.f) + 1e-8f) * riem_scale; \
    float gra = gr * gr * grass_scale; \
    CONVROW(r) }

#define SM1(o,r) { \
    float yv = y##o##_##r + Bb; y##o##_##r = yv; \
    float mx = yv; \
    mx = fmaxf(mx, __shfl_xor(mx, 1, 64)); \
    mx = fmaxf(mx, __shfl_xor(mx, 2, 64)); \
    mx = fmaxf(mx, __shfl_xor(mx, 4, 64)); \
    mx = fmaxf(mx, __shfl_xor(mx, 8, 64)); \
    if (rowL == 0) red[(o * 16 + g * 4 + r) * 8 + w] = mx; }
#define SM1o(o) { const float Bb = Bbn_s[obase + o]; SM1(o,0) SM1(o,1) SM1(o,2) SM1(o,3) }

#define SM2(o,r) { \
    int row = g * 4 + r; \
    float mn = mrun_s[o * 16 + row]; \
    float p = expf(y##o##_##r - mn); \
    unsigned us = bf16r(p); \
    float pr = __uint_as_float(us << 16); \
    P_s[(o * 16 + row) * 128 + (((m_ >> 3) ^ (row & 7)) << 3) + (m_ & 7)] = (unsigned short)us; \
    float s = pr; \
    s += __shfl_xor(s, 1, 64); s += __shfl_xor(s, 2, 64); \
    s += __shfl_xor(s, 4, 64); s += __shfl_xor(s, 8, 64); \
    if (rowL == 0) red[(o * 16 + row) * 8 + w] = s; \
    y##o##_##r = 0.f; }
#define SM2o(o) { SM2(o,0) SM2(o,1) SM2(o,2) SM2(o,3) }

#define PVSTEP(o) { \
    { const unsigned* vp = vpk + ((size_t)(b * 12 + obase + o) << 16) + (size_t)m0 * 64; \
      int d_ = tid & 63; int mb0v = (tid >> 6) * 4; int mcb = (tid >> 6); \
      uint4 v0 = ld4v(vp, mb0v, d_);      uint4 v1 = ld4v(vp, mb0v + 32, d_); \
      uint4 v2 = ld4v(vp, mb0v + 64, d_); uint4 v3 = ld4v(vp, mb0v + 96, d_); \
      *(uint4*)&vt_s[d_ * 128 + (((mcb + 0)  ^ (d_ & 15)) << 2)] = v0; \
      *(uint4*)&vt_s[d_ * 128 + (((mcb + 8)  ^ (d_ & 15)) << 2)] = v1; \
      *(uint4*)&vt_s[d_ * 128 + (((mcb + 16) ^ (d_ & 15)) << 2)] = v2; \
      *(uint4*)&vt_s[d_ * 128 + (((mcb + 24) ^ (d_ & 15)) << 2)] = v3; } \
    __syncthreads(); \
    { float c0_ = coS_s[o * 16 + g * 4 + 0], c1_ = coS_s[o * 16 + g * 4 + 1]; \
      float c2_ = coS_s[o * 16 + g * 4 + 2], c3_ = coS_s[o * 16 + g * 4 + 3]; \
      acc##o[0] *= c0_; acc##o[1] *= c1_; acc##o[2] *= c2_; acc##o[3] *= c3_; } \
    { int mc8 = km * 8 + 0 * 4 + g; \
      short8 pa = *(const short8*)&P_s[(o * 16 + rowL) * 128 + ((mc8 ^ r7) << 3)]; \
      int c0 = km * 16 + 0 * 8 + g * 2; \
      const unsigned* vrow = &vt_s[(wd * 16 + rowL) * 128]; \
      uint4 b0 = *(const uint4*)&vrow[((c0 ^ rowL) << 2)]; \
      uint4 b1 = *(const uint4*)&vrow[(((c0 + 1) ^ rowL) << 2)]; \
      short8 vh = mk_hi(b0, b1), vl = mk_lo(b0, b1); \
      acc##o = MFMA(pa, vh, acc##o); acc##o = MFMA(pa, vl, acc##o); } \
    { int mc8 = km * 8 + 1 * 4 + g; \
      short8 pa = *(const short8*)&P_s[(o * 16 + rowL) * 128 + ((mc8 ^ r7) << 3)]; \
      int c0 = km * 16 + 1 * 8 + g * 2; \
      const unsigned* vrow = &vt_s[(wd * 16 + rowL) * 128]; \
      uint4 b0 = *(const uint4*)&vrow[((c0 ^ rowL) << 2)]; \
      uint4 b1 = *(const uint4*)&vrow[(((c0 + 1) ^ rowL) << 2)]; \
      short8 vh = mk_hi(b0, b1), vl = mk_lo(b0, b1); \
      acc##o = MFMA(pa, vh, acc##o); acc##o = MFMA(pa, vl, acc##o); } \
    __syncthreads(); }

#define EPI(o) { \
    if (km == 1) { \
      mb[(g * 4 + 0) * 64 + wd * 16 + rowL] = acc##o[0]; \
      mb[(g * 4 + 1) * 64 + wd * 16 + rowL] = acc##o[1]; \
      mb[(g * 4 + 2) * 64 + wd * 16 + rowL] = acc##o[2]; \
      mb[(g * 4 + 3) * 64 + wd * 16 + rowL] = acc##o[3]; } \
    __syncthreads(); \
    if (km == 0) { \
      { int row = g * 4 + 0; float tot = acc##o[0] + mb[row * 64 + wd * 16 + rowL]; \
        attno[((size_t)(b * 1024 + n0 + row)) * 768 + (obase + o) * 64 + wd * 16 + rowL] = tot / lrun_s[o * 16 + row]; } \
      { int row = g * 4 + 1; float tot = acc##o[1] + mb[row * 64 + wd * 16 + rowL]; \
        attno[((size_t)(b * 1024 + n0 + row)) * 768 + (obase + o) * 64 + wd * 16 + rowL] = tot / lrun_s[o * 16 + row]; } \
      { int row = g * 4 + 2; float tot = acc##o[2] + mb[row * 64 + wd * 16 + rowL]; \
        attno[((size_t)(b * 1024 + n0 + row)) * 768 + (obase + o) * 64 + wd * 16 + rowL] = tot / lrun_s[o * 16 + row]; } \
      { int row = g * 4 + 3; float tot = acc##o[3] + mb[row * 64 + wd * 16 + rowL]; \
        attno[((size_t)(b * 1024 + n0 + row)) * 768 + (obase + o) * 64 + wd * 16 + rowL] = tot / lrun_s[o * 16 + row]; } } \
    __syncthreads(); }

__global__ __launch_bounds__(512) void attn_fused(
    const unsigned* __restrict__ qpk, const unsigned* __restrict__ kpk, const unsigned* __restrict__ vpk,
    const unsigned short* __restrict__ qgrh, const unsigned short* __restrict__ kgrh,
    const float* __restrict__ qn4g, const float* __restrict__ kn4g,
    const float* __restrict__ cw, const float* __restrict__ conv_b,
    const float* __restrict__ bn_gamma, const float* __restrict__ bn_beta,
    const float* __restrict__ bn_mean, const float* __restrict__ bn_var,
    const float* __restrict__ scale_p, const float* __restrict__ riem_p,
    const float* __restrict__ grass_p, float* __restrict__ attno)
{
    extern __shared__ char smem[];
    unsigned* qs   = (unsigned*)(smem);
    unsigned short* qgs  = (unsigned short*)(smem + 49152);
    unsigned* kL   = (unsigned*)(smem + 73728);
    unsigned short* kgrL = (unsigned short*)(smem + 106496);
    unsigned short* P_s  = (unsigned short*)(smem + 73728);   // [6][16][128] overlays kL
    unsigned* vt_s = (unsigned*)(smem + 122880);
    float* red     = (float*)(smem + 122880);                  // [96][8] overlays vt
    float* mb      = (float*)(smem + 122880);                  // [16][64] overlays vt
    float* Bbn_s   = (float*)(smem + 155648);                  // [12]
    float* qn4s    = Bbn_s + 12;                               // [12][16]
    float* mrun_s  = qn4s + 192;                               // [96]
    float* lrun_s  = mrun_s + 96;                              // [96]
    float* coS_s   = lrun_s + 96;                              // [96]
    float* cwS_s   = coS_s + 96;                               // [12][36] BN-scaled conv w

    const int tid = threadIdx.x;
    const int lane = tid & 63;
    const int w = tid >> 6;
    const int rowL = lane & 15;
    const int g = lane >> 4;
    const int r7 = rowL & 7;
    const int km = w >> 2, wd = w & 3;
    const int b = blockIdx.y;
    const int n0 = blockIdx.x * 16;
    const int obase = blockIdx.z * 6;
    const float scale = scale_p[0], riem_scale = riem_p[0], grass_scale = grass_p[0];

    if (tid < 432) {
        int o = tid / 36;
        float inv = bn_gamma[o] * rsqrtf(bn_var[o] + 1e-5f);
        cwS_s[tid] = cw[tid] * inv;
    }
    if (tid >= 448 && tid < 460) {
        int o = tid - 448;
        float inv = bn_gamma[o] * rsqrtf(bn_var[o] + 1e-5f);
        Bbn_s[o] = fmaf(conv_b[o] - bn_mean[o], inv, bn_beta[o]);
    }
    if (tid < 96) { mrun_s[tid] = -1e30f; lrun_s[tid] = 0.f; }
    if (tid < 192) qn4s[tid] = qn4g[(size_t)(b * 12 + (tid >> 4)) * 1024 + n0 + (tid & 15)];
    // stage q packed + qgr (once; visibility covered by the first compute-phase barrier)
#pragma unroll
    for (int e = 0; e < 6; e++) {
        int ci = tid + 512 * e;
        int R = ci >> 4, c = ci & 15;
        const unsigned* gp = qpk + ((size_t)(b * 12 + (R >> 4)) << 16) + (size_t)(n0 + (R & 15)) * 64 + c * 4;
        uint4 v = *(const uint4*)gp;
        *(uint4*)&qs[R * 64 + ((c ^ (R & 7)) << 2)] = v;
    }
#pragma unroll
    for (int e = 0; e < 3; e++) {
        int ci = tid + 512 * e;
        int R = ci >> 3, c = ci & 7;
        const unsigned short* gp = qgrh + ((size_t)(b * 12 + (R >> 4)) << 16) + (size_t)(n0 + (R & 15)) * 64 + c * 8;
        uint4 v = *(const uint4*)gp;
        *(uint4*)&qgs[R * 64 + ((c ^ (R & 7)) << 3)] = v;
    }

    EACH_O6(DECL_Y)
    EACH_O6(DECL_A)

    uint4 kreg[4], kgreg[2];

    for (int m0 = 0; m0 < 1024; m0 += 128) {
        // ---------- scores over all 12 heads ----------
        for (int h = 0; h < 12; h++) {
            if (h == 0) {
                const unsigned* kp = kpk + ((size_t)(b * 12) << 16) + (size_t)m0 * 64;
                const unsigned short* kg = kgrh + ((size_t)(b * 12) << 16) + (size_t)m0 * 64;
#pragma unroll
                for (int e = 0; e < 4; e++) { int ci = tid + 512 * e; kreg[e] = *(const uint4*)&kp[(size_t)(ci >> 4) * 64 + (ci & 15) * 4]; }
#pragma unroll
                for (int e = 0; e < 2; e++) { int ci = tid + 512 * e; kgreg[e] = *(const uint4*)&kg[(size_t)(ci >> 3) * 64 + (ci & 7) * 8]; }
            }
#pragma unroll
            for (int e = 0; e < 4; e++) {
                int ci = tid + 512 * e; int m = ci >> 4, c = ci & 15;
                *(uint4*)&kL[m * 64 + ((c ^ (m & 7)) << 2)] = kreg[e];
            }
#pragma unroll
            for (int e = 0; e < 2; e++) {
                int ci = tid + 512 * e; int m = ci >> 3, c = ci & 7;
                *(uint4*)&kgrL[m * 64 + ((c ^ (m & 7)) << 3)] = kgreg[e];
            }
            if (h < 11) {
                const unsigned* kp = kpk + ((size_t)(b * 12 + h + 1) << 16) + (size_t)m0 * 64;
                const unsigned short* kg = kgrh + ((size_t)(b * 12 + h + 1) << 16) + (size_t)m0 * 64;
#pragma unroll
                for (int e = 0; e < 4; e++) { int ci = tid + 512 * e; kreg[e] = *(const uint4*)&kp[(size_t)(ci >> 4) * 64 + (ci & 15) * 4]; }
#pragma unroll
                for (int e = 0; e < 2; e++) { int ci = tid + 512 * e; kgreg[e] = *(const uint4*)&kg[(size_t)(ci >> 3) * 64 + (ci & 7) * 8]; }
            }
            __syncthreads();

            float kn4v = kn4g[(size_t)(b * 12 + h) * 1024 + m0 + w * 16 + rowL];
            f32x4 s1 = {0,0,0,0}, s2 = {0,0,0,0};
#pragma unroll
            for (int ks = 0; ks < 2; ks++) {
                int c0 = ks * 8 + g * 2;
                const unsigned* qrow = &qs[(h * 16 + rowL) * 64];
                uint4 a0 = *(const uint4*)&qrow[((c0 ^ r7) << 2)];
                uint4 a1 = *(const uint4*)&qrow[(((c0 + 1) ^ r7) << 2)];
                const unsigned* krow = &kL[(w * 16 + rowL) * 64];
                uint4 b0 = *(const uint4*)&krow[((c0 ^ r7) << 2)];
                uint4 b1 = *(const uint4*)&krow[(((c0 + 1) ^ r7) << 2)];
                short8 qhi = mk_hi(a0, a1), qlo = mk_lo(a0, a1);
                short8 khi = mk_hi(b0, b1), klo = mk_lo(b0, b1);
                s1 = MFMA(qhi, khi, s1);
                s1 = MFMA(qhi, klo, s1);
                s1 = MFMA(qlo, khi, s1);
                int cg = ks * 4 + g;
                short8 qg = *(const short8*)&qgs[(h * 16 + rowL) * 64 + ((cg ^ r7) << 3)];
                short8 kg2 = *(const short8*)&kgrL[(w * 16 + rowL) * 64 + ((cg ^ r7) << 3)];
                s2 = MFMA(qg, kg2, s2);
            }
            EACH_O6(LOADC)
            SCORE_R(0) SCORE_R(1) SCORE_R(2) SCORE_R(3)
            __syncthreads();
        }

        // ---------- BN shift + online softmax (6 channels) ----------
        EACH_O6(SM1o)
        __syncthreads(); // B1
        if (tid < 96) {
            float m8 = red[tid * 8];
#pragma unroll
            for (int j = 1; j < 8; j++) m8 = fmaxf(m8, red[tid * 8 + j]);
            float mo = mrun_s[tid];
            float mn = fmaxf(mo, m8);
            mrun_s[tid] = mn;
            coS_s[tid] = expf(mo - mn);
        }
        __syncthreads(); // B2
        {
            int m_ = w * 16 + rowL;
            EACH_O6(SM2o)
        }
        __syncthreads(); // B3
        if (tid < 96) {
            float s8 = 0.f;
#pragma unroll
            for (int j = 0; j < 8; j++) s8 += red[tid * 8 + j];
            lrun_s[tid] = fmaf(lrun_s[tid], coS_s[tid], s8);
        }
        __syncthreads(); // B4

        // ---------- PV over this block's 6 channels ----------
        EACH_O6(PVSTEP)
    }

    // ---------- epilogue: merge km halves, normalize, store ----------
    EACH_O6(EPI)
}

// ---------------- K4: out = attno @ proj_w^T + proj_b ----------------
__global__ __launch_bounds__(256) void proj_gemm(
    const float* __restrict__ x, const float* __restrict__ w, const float* __restrict__ bias,
    float* __restrict__ out)
{
    __shared__ float As[16][68];
    __shared__ float Ws[16][68];
    const int tid = threadIdx.x;
    const int m0 = blockIdx.x * 64;
    const int c0 = blockIdx.y * 64;
    const int ty = tid >> 4, tx = tid & 15;
    const int lm = tid >> 2;
    const int lk = (tid & 3) * 4;
    float acc[4][4];
#pragma unroll
    for (int i = 0; i < 4; i++)
#pragma unroll
        for (int j = 0; j < 4; j++) acc[i][j] = 0.f;

    for (int kk0 = 0; kk0 < 768; kk0 += 16) {
        float4 av = *(const float4*)&x[(m0 + lm) * 768 + kk0 + lk];
        float4 wv = *(const float4*)&w[(c0 + lm) * 768 + kk0 + lk];
        __syncthreads();
        As[lk + 0][lm] = av.x; As[lk + 1][lm] = av.y; As[lk + 2][lm] = av.z; As[lk + 3][lm] = av.w;
        Ws[lk + 0][lm] = wv.x; Ws[lk + 1][lm] = wv.y; Ws[lk + 2][lm] = wv.z; Ws[lk + 3][lm] = wv.w;
        __syncthreads();
#pragma unroll
        for (int kk = 0; kk < 16; kk++) {
            float4 a  = *(const float4*)&As[kk][ty * 4];
            float4 bv = *(const float4*)&Ws[kk][tx * 4];
            acc[0][0] += a.x * bv.x; acc[0][1] += a.x * bv.y; acc[0][2] += a.x * bv.z; acc[0][3] += a.x * bv.w;
            acc[1][0] += a.y * bv.x; acc[1][1] += a.y * bv.y; acc[1][2] += a.y * bv.z; acc[1][3] += a.y * bv.w;
            acc[2][0] += a.z * bv.x; acc[2][1] += a.z * bv.y; acc[2][2] += a.z * bv.z; acc[2][3] += a.z * bv.w;
            acc[3][0] += a.w * bv.x; acc[3][1] += a.w * bv.y; acc[3][2] += a.w * bv.z; acc[3][3] += a.w * bv.w;
        }
    }
#pragma unroll
    for (int i = 0; i < 4; i++) {
        int row = m0 + ty * 4 + i;
#pragma unroll
        for (int j = 0; j < 4; j++) {
            int col = c0 + tx * 4 + j;
            out[(size_t)row * 768 + col] = acc[i][j] + bias[col];
        }
    }
}

extern "C" void kernel_launch(void* const* d_in, const int* in_sizes, int n_in,
                              void* d_out, int out_size, void* d_ws, size_t ws_size,
                              hipStream_t stream) {
    const float* x          = (const float*)d_in[0];
    const float* qkv_w      = (const float*)d_in[1];
    const float* qkv_b      = (const float*)d_in[2];
    const float* proj_w     = (const float*)d_in[3];
    const float* proj_b     = (const float*)d_in[4];
    const float* scale      = (const float*)d_in[5];
    const float* riem_scale = (const float*)d_in[6];
    const float* grass_scale= (const float*)d_in[7];
    const float* conv_w     = (const float*)d_in[8];
    const float* conv_b     = (const float*)d_in[9];
    const float* bn_gamma   = (const float*)d_in[10];
    const float* bn_beta    = (const float*)d_in[11];
    const float* bn_mean    = (const float*)d_in[12];
    const float* bn_var     = (const float*)d_in[13];
    float* out = (float*)d_out;

    float* q   = (float*)d_ws;                 // 3145728 f32 ; later aliased as attno
    float* k   = q + 3145728;
    unsigned* qpk = (unsigned*)(k + 3145728);
    unsigned* kpk = qpk + 3145728;
    unsigned* vpk = kpk + 3145728;
    unsigned short* qgrh = (unsigned short*)(vpk + 3145728);
    unsigned short* kgrh = qgrh + 3145728;
    float* qn4 = (float*)(kgrh + 3145728);
    float* kn4 = qn4 + 49152;
    float* attno = q; // alias: q f32 dead after qr_kernel/row_norms

    hipLaunchKernelGGL(qkv_gemm, dim3(64, 36), dim3(256), 0, stream,
                       x, qkv_w, qkv_b, q, k, qpk, kpk, vpk);
    hipLaunchKernelGGL(row_norms, dim3(24576), dim3(256), 0, stream, q, k, qn4, kn4);
    hipLaunchKernelGGL(qr_kernel, dim3(96), dim3(1024), 0, stream, q, k, qgrh, kgrh);

    hipFuncSetAttribute(reinterpret_cast<const void*>(attn_fused),
                        hipFuncAttributeMaxDynamicSharedMemorySize, SM_BYTES);
    hipLaunchKernelGGL(attn_fused, dim3(64, 4, 2), dim3(512), SM_BYTES, stream,
                       qpk, kpk, vpk, qgrh, kgrh, qn4, kn4, conv_w, conv_b,
                       bn_gamma, bn_beta, bn_mean, bn_var,
                       scale, riem_scale, grass_scale, attno);
    hipLaunchKernelGGL(proj_gemm, dim3(64, 12), dim3(256), 0, stream,
                       attno, proj_w, proj_b, out);
}

// Round 8
// 1025.987 us; speedup vs baseline: 1.7674x; 1.7674x over previous
//
#include <hip/hip_runtime.h>
#include <math.h>

// B=4, N=1024, C=768, H=12, D=64
// ws: q[12.58MB] k qpk kpk vpk qgrh kgrh qn4 kn4  (= 75,890,688 B base)
// + S~ logits buffer (f32) if ws_size permits. attno aliases q.

typedef __attribute__((ext_vector_type(8))) short short8;
typedef __attribute__((ext_vector_type(4))) float f32x4;

__device__ __forceinline__ unsigned bf16r(float x) {
    unsigned u = __float_as_uint(x);
    return (u + 0x7FFFu + ((u >> 16) & 1u)) >> 16;
}
__device__ __forceinline__ unsigned packhl(float x) {
    unsigned u = __float_as_uint(x);
    unsigned hi = (u + 0x7FFFu + ((u >> 16) & 1u)) & 0xFFFF0000u;
    float lo = x - __uint_as_float(hi);
    unsigned ul = __float_as_uint(lo);
    unsigned l16 = (ul + 0x7FFFu + ((ul >> 16) & 1u)) >> 16;
    return hi | (l16 & 0xFFFFu);
}
union U4S8 { uint4 u; short8 s; };
__device__ __forceinline__ short8 mk_hi(uint4 a, uint4 b) {
    U4S8 r;
    r.u.x = __builtin_amdgcn_perm(a.y, a.x, 0x07060302);
    r.u.y = __builtin_amdgcn_perm(a.w, a.z, 0x07060302);
    r.u.z = __builtin_amdgcn_perm(b.y, b.x, 0x07060302);
    r.u.w = __builtin_amdgcn_perm(b.w, b.z, 0x07060302);
    return r.s;
}
__device__ __forceinline__ short8 mk_lo(uint4 a, uint4 b) {
    U4S8 r;
    r.u.x = __builtin_amdgcn_perm(a.y, a.x, 0x05040100);
    r.u.y = __builtin_amdgcn_perm(a.w, a.z, 0x05040100);
    r.u.z = __builtin_amdgcn_perm(b.y, b.x, 0x05040100);
    r.u.w = __builtin_amdgcn_perm(b.w, b.z, 0x05040100);
    return r.s;
}
__device__ __forceinline__ uint4 ld4v(const unsigned* vp, int mbase, int d) {
    uint4 r;
    r.x = vp[(size_t)(mbase + 0) * 64 + d];
    r.y = vp[(size_t)(mbase + 1) * 64 + d];
    r.z = vp[(size_t)(mbase + 2) * 64 + d];
    r.w = vp[(size_t)(mbase + 3) * 64 + d];
    return r;
}
#define MFMA(a,b,c) __builtin_amdgcn_mfma_f32_16x16x32_bf16(a, b, c, 0, 0, 0)

// ---------------- K1: qkv GEMM + scatter (f32 + packed hi/lo bf16) ----------------
__global__ __launch_bounds__(256) void qkv_gemm(
    const float* __restrict__ x, const float* __restrict__ w, const float* __restrict__ bias,
    float* __restrict__ q, float* __restrict__ k,
    unsigned* __restrict__ qpk, unsigned* __restrict__ kpk, unsigned* __restrict__ vpk)
{
    __shared__ float As[16][68];
    __shared__ float Ws[16][68];
    const int tid = threadIdx.x;
    const int m0 = blockIdx.x * 64;
    const int c0 = blockIdx.y * 64;
    const int ty = tid >> 4, tx = tid & 15;
    const int lm = tid >> 2;
    const int lk = (tid & 3) * 4;
    float acc[4][4];
#pragma unroll
    for (int i = 0; i < 4; i++)
#pragma unroll
        for (int j = 0; j < 4; j++) acc[i][j] = 0.f;

    for (int kk0 = 0; kk0 < 768; kk0 += 16) {
        float4 av = *(const float4*)&x[(m0 + lm) * 768 + kk0 + lk];
        float4 wv = *(const float4*)&w[(c0 + lm) * 768 + kk0 + lk];
        __syncthreads();
        As[lk + 0][lm] = av.x; As[lk + 1][lm] = av.y; As[lk + 2][lm] = av.z; As[lk + 3][lm] = av.w;
        Ws[lk + 0][lm] = wv.x; Ws[lk + 1][lm] = wv.y; Ws[lk + 2][lm] = wv.z; Ws[lk + 3][lm] = wv.w;
        __syncthreads();
#pragma unroll
        for (int kk = 0; kk < 16; kk++) {
            float4 a  = *(const float4*)&As[kk][ty * 4];
            float4 bv = *(const float4*)&Ws[kk][tx * 4];
            acc[0][0] += a.x * bv.x; acc[0][1] += a.x * bv.y; acc[0][2] += a.x * bv.z; acc[0][3] += a.x * bv.w;
            acc[1][0] += a.y * bv.x; acc[1][1] += a.y * bv.y; acc[1][2] += a.y * bv.z; acc[1][3] += a.y * bv.w;
            acc[2][0] += a.z * bv.x; acc[2][1] += a.z * bv.y; acc[2][2] += a.z * bv.z; acc[2][3] += a.z * bv.w;
            acc[3][0] += a.w * bv.x; acc[3][1] += a.w * bv.y; acc[3][2] += a.w * bv.z; acc[3][3] += a.w * bv.w;
        }
    }
#pragma unroll
    for (int i = 0; i < 4; i++) {
        int row = m0 + ty * 4 + i;
        int bb = row >> 10, n = row & 1023;
#pragma unroll
        for (int j = 0; j < 4; j++) {
            int col = c0 + tx * 4 + j;
            float val = acc[i][j] + bias[col];
            int s = (col >= 1536) ? 2 : ((col >= 768) ? 1 : 0);
            int hc = col - s * 768;
            size_t idx = ((size_t)(bb * 12 + (hc >> 6)) << 16) + ((size_t)n << 6) + (hc & 63);
            if (s == 0)      { q[idx] = val; qpk[idx] = packhl(val); }
            else if (s == 1) { k[idx] = val; kpk[idx] = packhl(val); }
            else             { vpk[idx] = packhl(val); }
        }
    }
}

// ---------------- K1b: squared row norms ----------------
__global__ __launch_bounds__(256) void row_norms(
    const float* __restrict__ q, const float* __restrict__ k,
    float* __restrict__ qn4, float* __restrict__ kn4)
{
    int wid = blockIdx.x * 4 + (threadIdx.x >> 6);
    int lane = threadIdx.x & 63;
    const float* src; float* dst; int r;
    if (wid < 49152) { src = q; dst = qn4; r = wid; }
    else             { src = k; dst = kn4; r = wid - 49152; }
    float xv = src[(size_t)r * 64 + lane];
    float s = xv * xv;
#pragma unroll
    for (int m = 1; m < 64; m <<= 1) s += __shfl_xor(s, m, 64);
    if (lane == 0) dst[r] = s * s;
}

// ---------------- K2: Householder QR (LAPACK signs), bf16 output ----------------
__global__ __launch_bounds__(1024) void qr_kernel(
    const float* __restrict__ q, const float* __restrict__ k,
    unsigned short* __restrict__ qgrh, unsigned short* __restrict__ kgrh)
{
    const int id = blockIdx.x;
    const float* src = (id & 1) ? k : q;
    unsigned short* dst = (id & 1) ? kgrh : qgrh;
    const int bh = id >> 1;
    src += (size_t)bh << 16;
    dst += (size_t)bh << 16;
    const int lane = threadIdx.x & 63;
    const int w = threadIdx.x >> 6;
    __shared__ float vbuf[1024];
    __shared__ float taub[64];

    float a[4][16];
#pragma unroll
    for (int c = 0; c < 4; c++)
#pragma unroll
        for (int i = 0; i < 16; i++)
            a[c][i] = src[(i * 64 + lane) * 64 + 4 * w + c];

    for (int d = 0; d < 64; d++) {
        const int wd = d >> 2, cd = d & 3;
        if (w == wd) {
#pragma unroll
            for (int c = 0; c < 4; c++) if (c == cd) {
                float part = 0.f;
#pragma unroll
                for (int i = 0; i < 16; i++) {
                    int r = i * 64 + lane; float xx = a[c][i];
                    part += (r >= d) ? xx * xx : 0.f;
                }
#pragma unroll
                for (int m = 1; m < 64; m <<= 1) part += __shfl_xor(part, m, 64);
                float sigma = part;
                float xd = __shfl(a[c][0], d, 64);
                float nrm = sqrtf(sigma);
                float beta = (xd >= 0.f) ? -nrm : nrm;
                float vd = xd - beta;
                float vtv = (sigma - xd * xd) + vd * vd;
                float tau2 = (vtv > 0.f) ? 2.f / vtv : 0.f;
                if (lane == d) a[c][0] = vd;
#pragma unroll
                for (int i = 0; i < 16; i++) {
                    int r = i * 64 + lane;
                    vbuf[r] = (r < d) ? 0.f : a[c][i];
                }
                if (lane == 0) taub[d] = tau2;
            }
        }
        __syncthreads();
        float t2 = taub[d];
#pragma unroll
        for (int c = 0; c < 4; c++) {
            int j = 4 * w + c;
            if (j > d) {
                float part = 0.f;
#pragma unroll
                for (int i = 0; i < 16; i++) part += vbuf[i * 64 + lane] * a[c][i];
#pragma unroll
                for (int m = 1; m < 64; m <<= 1) part += __shfl_xor(part, m, 64);
                float sv = t2 * part;
#pragma unroll
                for (int i = 0; i < 16; i++) a[c][i] -= sv * vbuf[i * 64 + lane];
            }
        }
        __syncthreads();
    }

    float qr[4][16];
#pragma unroll
    for (int c = 0; c < 4; c++)
#pragma unroll
        for (int i = 0; i < 16; i++) {
            int r = i * 64 + lane;
            qr[c][i] = (r == 4 * w + c) ? 1.f : 0.f;
        }
    for (int d = 63; d >= 0; d--) {
        const int wd = d >> 2, cd = d & 3;
        if (w == wd) {
#pragma unroll
            for (int c = 0; c < 4; c++) if (c == cd) {
#pragma unroll
                for (int i = 0; i < 16; i++) {
                    int r = i * 64 + lane;
                    vbuf[r] = (r < d) ? 0.f : a[c][i];
                }
            }
        }
        __syncthreads();
        float t2 = taub[d];
#pragma unroll
        for (int c = 0; c < 4; c++) {
            int j = 4 * w + c;
            if (j >= d) {
                float part = 0.f;
#pragma unroll
                for (int i = 0; i < 16; i++) part += vbuf[i * 64 + lane] * qr[c][i];
#pragma unroll
                for (int m = 1; m < 64; m <<= 1) part += __shfl_xor(part, m, 64);
                float sv = t2 * part;
#pragma unroll
                for (int i = 0; i < 16; i++) qr[c][i] -= sv * vbuf[i * 64 + lane];
            }
        }
        __syncthreads();
    }
#pragma unroll
    for (int c = 0; c < 4; c++)
#pragma unroll
        for (int i = 0; i < 16; i++)
            dst[(i * 64 + lane) * 64 + 4 * w + c] = (unsigned short)bf16r(qr[c][i]);
}

// ================= SPLIT PATH =================
// Kernel S: scores+conv+BN -> S~ [nb][12][1024][1024] f32.
// Block: 256 thr / 4 waves (wave = m-quad of 16), tile n=16 x m=64, 6 of 12 channels.
// Grid: (16 mtiles, 64 ntiles x 2 ohalf, nb). y regs = 24; cw via uniform s_load.

#define SC_EACH(F) F(0) F(1) F(2) F(3) F(4) F(5)
#define SC_DECLY(o) float y##o##_0 = 0.f, y##o##_1 = 0.f, y##o##_2 = 0.f, y##o##_3 = 0.f;
#define SC_LOADC(o) const float cA##o = cw[(obase + o) * 36 + h], \
                                cB##o = cw[(obase + o) * 36 + 12 + h], \
                                cC##o = cw[(obase + o) * 36 + 24 + h];
#define SC_CONV1(o,r) y##o##_##r = fmaf(cA##o, att, fmaf(cB##o, rie, fmaf(cC##o, gra, y##o##_##r)));
#define SC_CONVROW(r) SC_CONV1(0,r) SC_CONV1(1,r) SC_CONV1(2,r) SC_CONV1(3,r) SC_CONV1(4,r) SC_CONV1(5,r)
#define SC_SCORE(r) { \
    float qk = s1[r], gr = s2[r]; \
    float qn4v = qn4s[g * 4 + r]; \
    float att = qk * scale; \
    float d2 = qn4v + kn4v - 2.f * qk * qk; \
    float rie = -sqrtf(fmaxf(d2, 0.f) + 1e-8f) * riem_scale; \
    float gra = gr * gr * grass_scale; \
    SC_CONVROW(r) }
#define SC_OUT(o) { \
    float inv = bn_gamma[obase + o] * rsqrtf(bn_var[obase + o] + 1e-5f); \
    float Bb = fmaf(conv_b[obase + o] - bn_mean[obase + o], inv, bn_beta[obase + o]); \
    float* dst = Sbuf + ((size_t)(z * 12 + obase + o) * 1024 + n0) * 1024 + m0 + w * 16 + rowL; \
    dst[(size_t)(g * 4 + 0) * 1024] = fmaf(y##o##_0, inv, Bb); \
    dst[(size_t)(g * 4 + 1) * 1024] = fmaf(y##o##_1, inv, Bb); \
    dst[(size_t)(g * 4 + 2) * 1024] = fmaf(y##o##_2, inv, Bb); \
    dst[(size_t)(g * 4 + 3) * 1024] = fmaf(y##o##_3, inv, Bb); }

__global__ __launch_bounds__(256) void sattn_scores(
    const unsigned* __restrict__ qpk, const unsigned* __restrict__ kpk,
    const unsigned short* __restrict__ qgrh, const unsigned short* __restrict__ kgrh,
    const float* __restrict__ qn4g, const float* __restrict__ kn4g,
    const float* __restrict__ cw, const float* __restrict__ conv_b,
    const float* __restrict__ bn_gamma, const float* __restrict__ bn_beta,
    const float* __restrict__ bn_mean, const float* __restrict__ bn_var,
    const float* __restrict__ scale_p, const float* __restrict__ riem_p,
    const float* __restrict__ grass_p, float* __restrict__ Sbuf, int b0)
{
    __shared__ unsigned qT[16 * 64];
    __shared__ unsigned short qgT[16 * 64];
    __shared__ unsigned kL[64 * 64];
    __shared__ unsigned short kgrL[64 * 64];
    __shared__ float qn4s[16];
    __shared__ float kn4s[64];

    const int tid = threadIdx.x;
    const int lane = tid & 63;
    const int w = tid >> 6;          // m-quad
    const int rowL = lane & 15;
    const int g = lane >> 4;
    const int r7 = rowL & 7;
    const int m0 = blockIdx.x * 64;
    const int n0 = (blockIdx.y >> 1) * 16;
    const int obase = (blockIdx.y & 1) * 6;
    const int z = blockIdx.z;
    const int b = b0 + z;
    const float scale = scale_p[0], riem_scale = riem_p[0], grass_scale = grass_p[0];

    SC_EACH(SC_DECLY)

    for (int h = 0; h < 12; h++) {
        __syncthreads();
        {   // stage q tile 16x64 u32
            int R = tid >> 4, c = tid & 15;
            uint4 v = *(const uint4*)&qpk[((size_t)(b * 12 + h) << 16) + (size_t)(n0 + R) * 64 + c * 4];
            *(uint4*)&qT[R * 64 + ((c ^ (R & 7)) << 2)] = v;
        }
        if (tid < 128) {
            int R = tid >> 3, c = tid & 7;
            uint4 v = *(const uint4*)&qgrh[((size_t)(b * 12 + h) << 16) + (size_t)(n0 + R) * 64 + c * 8];
            *(uint4*)&qgT[R * 64 + ((c ^ (R & 7)) << 3)] = v;
        }
#pragma unroll
        for (int e = 0; e < 4; e++) {
            int ci = tid + 256 * e; int m = ci >> 4, c = ci & 15;
            uint4 v = *(const uint4*)&kpk[((size_t)(b * 12 + h) << 16) + (size_t)(m0 + m) * 64 + c * 4];
            *(uint4*)&kL[m * 64 + ((c ^ (m & 7)) << 2)] = v;
        }
#pragma unroll
        for (int e = 0; e < 2; e++) {
            int ci = tid + 256 * e; int m = ci >> 3, c = ci & 7;
            uint4 v = *(const uint4*)&kgrh[((size_t)(b * 12 + h) << 16) + (size_t)(m0 + m) * 64 + c * 8];
            *(uint4*)&kgrL[m * 64 + ((c ^ (m & 7)) << 3)] = v;
        }
        if (tid < 64) kn4s[tid] = kn4g[(size_t)(b * 12 + h) * 1024 + m0 + tid];
        if (tid < 16) qn4s[tid] = qn4g[(size_t)(b * 12 + h) * 1024 + n0 + tid];
        __syncthreads();

        float kn4v = kn4s[w * 16 + rowL];
        f32x4 s1 = {0,0,0,0}, s2 = {0,0,0,0};
#pragma unroll
        for (int ks = 0; ks < 2; ks++) {
            int c0 = ks * 8 + g * 2;
            uint4 a0 = *(const uint4*)&qT[rowL * 64 + ((c0 ^ r7) << 2)];
            uint4 a1 = *(const uint4*)&qT[rowL * 64 + (((c0 + 1) ^ r7) << 2)];
            uint4 b0v = *(const uint4*)&kL[(w * 16 + rowL) * 64 + ((c0 ^ r7) << 2)];
            uint4 b1v = *(const uint4*)&kL[(w * 16 + rowL) * 64 + (((c0 + 1) ^ r7) << 2)];
            short8 qhi = mk_hi(a0, a1), qlo = mk_lo(a0, a1);
            short8 khi = mk_hi(b0v, b1v), klo = mk_lo(b0v, b1v);
            s1 = MFMA(qhi, khi, s1);
            s1 = MFMA(qhi, klo, s1);
            s1 = MFMA(qlo, khi, s1);
            int cg = ks * 4 + g;
            short8 qg = *(const short8*)&qgT[rowL * 64 + ((cg ^ r7) << 3)];
            short8 kg2 = *(const short8*)&kgrL[(w * 16 + rowL) * 64 + ((cg ^ r7) << 3)];
            s2 = MFMA(qg, kg2, s2);
        }
        SC_EACH(SC_LOADC)
        SC_SCORE(0) SC_SCORE(1) SC_SCORE(2) SC_SCORE(3)
    }
    SC_EACH(SC_OUT)
}

// Kernel P: online softmax + PV per (ntile16, o, b). 256 thr / 4 waves (wave = d-quad).
__global__ __launch_bounds__(256) void sattn_pv(
    const unsigned* __restrict__ vpk, const float* __restrict__ Sbuf,
    float* __restrict__ attno, int b0)
{
    __shared__ unsigned short P_s[16 * 64];
    __shared__ unsigned vt_s[64 * 64];
    __shared__ float mrun[16], lrun[16], cos_[16];

    const int tid = threadIdx.x;
    const int lane = tid & 63;
    const int w = tid >> 6;          // d-quad
    const int rowL = lane & 15;
    const int g = lane >> 4;
    const int r7 = rowL & 7;
    const int n0 = blockIdx.x * 16;
    const int o = blockIdx.y;
    const int z = blockIdx.z;
    const int b = b0 + z;
    const int srow = tid >> 4;       // softmax row 0..15 (wave-exclusive: wave owns 4 rows)
    const int sc4 = (tid & 15) * 4;  // m offset within step

    if (tid < 16) { mrun[tid] = -1e30f; lrun[tid] = 0.f; }
    f32x4 acc = {0,0,0,0};
    const float* Srow = Sbuf + ((size_t)(z * 12 + o) * 1024 + n0 + srow) * 1024;
    const unsigned* vp = vpk + ((size_t)(b * 12 + o) << 16);
    __syncthreads();

    for (int m0 = 0; m0 < 1024; m0 += 64) {
        float4 sv = *(const float4*)&Srow[m0 + sc4];
        float mx = fmaxf(fmaxf(sv.x, sv.y), fmaxf(sv.z, sv.w));
        mx = fmaxf(mx, __shfl_xor(mx, 1, 64));
        mx = fmaxf(mx, __shfl_xor(mx, 2, 64));
        mx = fmaxf(mx, __shfl_xor(mx, 4, 64));
        mx = fmaxf(mx, __shfl_xor(mx, 8, 64));
        float mo = mrun[srow];
        float mn = fmaxf(mo, mx);
        float co = expf(mo - mn);
        float p0 = expf(sv.x - mn), p1 = expf(sv.y - mn), p2 = expf(sv.z - mn), p3 = expf(sv.w - mn);
        unsigned u0 = bf16r(p0), u1 = bf16r(p1), u2 = bf16r(p2), u3 = bf16r(p3);
        {
            ushort4 pw = make_ushort4((unsigned short)u0, (unsigned short)u1,
                                      (unsigned short)u2, (unsigned short)u3);
            *(ushort4*)&P_s[srow * 64 + (((sc4 >> 3) ^ (srow & 7)) << 3) + (sc4 & 7)] = pw;
        }
        float ps = __uint_as_float(u0 << 16) + __uint_as_float(u1 << 16)
                 + __uint_as_float(u2 << 16) + __uint_as_float(u3 << 16);
        ps += __shfl_xor(ps, 1, 64); ps += __shfl_xor(ps, 2, 64);
        ps += __shfl_xor(ps, 4, 64); ps += __shfl_xor(ps, 8, 64);
        if ((lane & 15) == 0) {
            mrun[srow] = mn;
            cos_[srow] = co;
            lrun[srow] = lrun[srow] * co + ps;
        }
        // stage V^T (packed hi|lo u32), chunk^(d&15) swizzle over 16 chunks
#pragma unroll
        for (int e = 0; e < 4; e++) {
            int d_ = tid & 63;
            int mb = (tid >> 6) * 4 + 16 * e;
            int mc = (tid >> 6) + 4 * e;
            uint4 v = ld4v(vp + (size_t)m0 * 64, mb, d_);
            *(uint4*)&vt_s[d_ * 64 + ((mc ^ (d_ & 15)) << 2)] = v;
        }
        __syncthreads();
        {
            float c0_ = cos_[g * 4 + 0], c1_ = cos_[g * 4 + 1];
            float c2_ = cos_[g * 4 + 2], c3_ = cos_[g * 4 + 3];
            acc[0] *= c0_; acc[1] *= c1_; acc[2] *= c2_; acc[3] *= c3_;
        }
        const int d_ = w * 16 + rowL;
        const unsigned* vrow = &vt_s[d_ * 64];
#pragma unroll
        for (int kk = 0; kk < 2; kk++) {
            int mc8 = kk * 4 + g;
            short8 pa = *(const short8*)&P_s[rowL * 64 + ((mc8 ^ r7) << 3)];
            int c0 = kk * 8 + g * 2;
            uint4 b0v = *(const uint4*)&vrow[((c0 ^ (d_ & 15)) << 2)];
            uint4 b1v = *(const uint4*)&vrow[(((c0 + 1) ^ (d_ & 15)) << 2)];
            short8 vh = mk_hi(b0v, b1v), vl = mk_lo(b0v, b1v);
            acc = MFMA(pa, vh, acc);
            acc = MFMA(pa, vl, acc);
        }
        __syncthreads();
    }
#pragma unroll
    for (int r = 0; r < 4; r++) {
        int row = g * 4 + r;
        attno[((size_t)(b * 1024 + n0 + row)) * 768 + o * 64 + w * 16 + rowL] = acc[r] / lrun[row];
    }
}

// ================= FUSED FALLBACK (round-7, used only if ws too small) =================
#define SM_BYTES 159360
#define EACH_O6(F) F(0) F(1) F(2) F(3) F(4) F(5)
#define DECL_Y(o) float y##o##_0 = 0.f, y##o##_1 = 0.f, y##o##_2 = 0.f, y##o##_3 = 0.f;
#define DECL_A(o) f32x4 acc##o = (f32x4){0.f, 0.f, 0.f, 0.f};
#define LOADC(o) const float cA##o = cwS_s[(obase + o) * 36 + h], \
                             cB##o = cwS_s[(obase + o) * 36 + 12 + h], \
                             cC##o = cwS_s[(obase + o) * 36 + 24 + h];
#define CONV1(o,r) y##o##_##r = fmaf(cA##o, att, fmaf(cB##o, rie, fmaf(cC##o, gra, y##o##_##r)));
#define CONVROW(r) CONV1(0,r) CONV1(1,r) CONV1(2,r) CONV1(3,r) CONV1(4,r) CONV1(5,r)
#define SCORE_R(r) { \
    float qk = s1[r], gr = s2[r]; \
    float qn4v = qn4s[h * 16 + g * 4 + r]; \
    float att = qk * scale; \
    float d2 = qn4v + kn4v - 2.f * qk * qk; \
    float rie = -sqrtf(fmaxf(d2, 0.f) + 1e-8f) * riem_scale; \
    float gra = gr * gr * grass_scale; \
    CONVROW(r) }
#define SM1(o,r) { \
    float yv = y##o##_##r + Bb; y##o##_##r = yv; \
    float mx = yv; \
    mx = fmaxf(mx, __shfl_xor(mx, 1, 64)); \
    mx = fmaxf(mx, __shfl_xor(mx, 2, 64)); \
    mx = fmaxf(mx, __shfl_xor(mx, 4, 64)); \
    mx = fmaxf(mx, __shfl_xor(mx, 8, 64)); \
    if (rowL == 0) red[(o * 16 + g * 4 + r) * 8 + w] = mx; }
#define SM1o(o) { const float Bb = Bbn_s[obase + o]; SM1(o,0) SM1(o,1) SM1(o,2) SM1(o,3) }
#define SM2(o,r) { \
    int row = g * 4 + r; \
    float mn = mrun_s[o * 16 + row]; \
    float p = expf(y##o##_##r - mn); \
    unsigned us = bf16r(p); \
    float pr = __uint_as_float(us << 16); \
    P_s[(o * 16 + row) * 128 + (((m_ >> 3) ^ (row & 7)) << 3) + (m_ & 7)] = (unsigned short)us; \
    float s = pr; \
    s += __shfl_xor(s, 1, 64); s += __shfl_xor(s, 2, 64); \
    s += __shfl_xor(s, 4, 64); s += __shfl_xor(s, 8, 64); \
    if (rowL == 0) red[(o * 16 + row) * 8 + w] = s; \
    y##o##_##r = 0.f; }
#define SM2o(o) { SM2(o,0) SM2(o,1) SM2(o,2) SM2(o,3) }
#define PVSTEP(o) { \
    { const unsigned* vp = vpk + ((size_t)(b * 12 + obase + o) << 16) + (size_t)m0 * 64; \
      int d_ = tid & 63; int mb0v = (tid >> 6) * 4; int mcb = (tid >> 6); \
      uint4 v0 = ld4v(vp, mb0v, d_);      uint4 v1 = ld4v(vp, mb0v + 32, d_); \
      uint4 v2 = ld4v(vp, mb0v + 64, d_); uint4 v3 = ld4v(vp, mb0v + 96, d_); \
      *(uint4*)&vt_s[d_ * 128 + (((mcb + 0)  ^ (d_ & 15)) << 2)] = v0; \
      *(uint4*)&vt_s[d_ * 128 + (((mcb + 8)  ^ (d_ & 15)) << 2)] = v1; \
      *(uint4*)&vt_s[d_ * 128 + (((mcb + 16) ^ (d_ & 15)) << 2)] = v2; \
      *(uint4*)&vt_s[d_ * 128 + (((mcb + 24) ^ (d_ & 15)) << 2)] = v3; } \
    __syncthreads(); \
    { float c0_ = coS_s[o * 16 + g * 4 + 0], c1_ = coS_s[o * 16 + g * 4 + 1]; \
      float c2_ = coS_s[o * 16 + g * 4 + 2], c3_ = coS_s[o * 16 + g * 4 + 3]; \
      acc##o[0] *= c0_; acc##o[1] *= c1_; acc##o[2] *= c2_; acc##o[3] *= c3_; } \
    { int mc8 = km * 8 + 0 * 4 + g; \
      short8 pa = *(const short8*)&P_s[(o * 16 + rowL) * 128 + ((mc8 ^ r7) << 3)]; \
      int c0 = km * 16 + 0 * 8 + g * 2; \
      const unsigned* vrow = &vt_s[(wd * 16 + rowL) * 128]; \
      uint4 b0 = *(const uint4*)&vrow[((c0 ^ rowL) << 2)]; \
      uint4 b1 = *(const uint4*)&vrow[(((c0 + 1) ^ rowL) << 2)]; \
      short8 vh = mk_hi(b0, b1), vl = mk_lo(b0, b1); \
      acc##o = MFMA(pa, vh, acc##o); acc##o = MFMA(pa, vl, acc##o); } \
    { int mc8 = km * 8 + 1 * 4 + g; \
      short8 pa = *(const short8*)&P_s[(o * 16 + rowL) * 128 + ((mc8 ^ r7) << 3)]; \
      int c0 = km * 16 + 1 * 8 + g * 2; \
      const unsigned* vrow = &vt_s[(wd * 16 + rowL) * 128]; \
      uint4 b0 = *(const uint4*)&vrow[((c0 ^ rowL) << 2)]; \
      uint4 b1 = *(const uint4*)&vrow[(((c0 + 1) ^ rowL) << 2)]; \
      short8 vh = mk_hi(b0, b1), vl = mk_lo(b0, b1); \
      acc##o = MFMA(pa, vh, acc##o); acc##o = MFMA(pa, vl, acc##o); } \
    __syncthreads(); }
#define EPI(o) { \
    if (km == 1) { \
      mb[(g * 4 + 0) * 64 + wd * 16 + rowL] = acc##o[0]; \
      mb[(g * 4 + 1) * 64 + wd * 16 + rowL] = acc##o[1]; \
      mb[(g * 4 + 2) * 64 + wd * 16 + rowL] = acc##o[2]; \
      mb[(g * 4 + 3) * 64 + wd * 16 + rowL] = acc##o[3]; } \
    __syncthreads(); \
    if (km == 0) { \
      { int row = g * 4 + 0; float tot = acc##o[0] + mb[row * 64 + wd * 16 + rowL]; \
        attno[((size_t)(b * 1024 + n0 + row)) * 768 + (obase + o) * 64 + wd * 16 + rowL] = tot / lrun_s[o * 16 + row]; } \
      { int row = g * 4 + 1; float tot = acc##o[1] + mb[row * 64 + wd * 16 + rowL]; \
        attno[((size_t)(b * 1024 + n0 + row)) * 768 + (obase + o) * 64 + wd * 16 + rowL] = tot / lrun_s[o * 16 + row]; } \
      { int row = g * 4 + 2; float tot = acc##o[2] + mb[row * 64 + wd * 16 + rowL]; \
        attno[((size_t)(b * 1024 + n0 + row)) * 768 + (obase + o) * 64 + wd * 16 + rowL] = tot / lrun_s[o * 16 + row]; } \
      { int row = g * 4 + 3; float tot = acc##o[3] + mb[row * 64 + wd * 16 + rowL]; \
        attno[((size_t)(b * 1024 + n0 + row)) * 768 + (obase + o) * 64 + wd * 16 + rowL] = tot / lrun_s[o * 16 + row]; } } \
    __syncthreads(); }

__global__ __launch_bounds__(512) void attn_fused(
    const unsigned* __restrict__ qpk, const unsigned* __restrict__ kpk, const unsigned* __restrict__ vpk,
    const unsigned short* __restrict__ qgrh, const unsigned short* __restrict__ kgrh,
    const float* __restrict__ qn4g, const float* __restrict__ kn4g,
    const float* __restrict__ cw, const float* __restrict__ conv_b,
    const float* __restrict__ bn_gamma, const float* __restrict__ bn_beta,
    const float* __restrict__ bn_mean, const float* __restrict__ bn_var,
    const float* __restrict__ scale_p, const float* __restrict__ riem_p,
    const float* __restrict__ grass_p, float* __restrict__ attno)
{
    extern __shared__ char smem[];
    unsigned* qs   = (unsigned*)(smem);
    unsigned short* qgs  = (unsigned short*)(smem + 49152);
    unsigned* kL   = (unsigned*)(smem + 73728);
    unsigned short* kgrL = (unsigned short*)(smem + 106496);
    unsigned short* P_s  = (unsigned short*)(smem + 73728);
    unsigned* vt_s = (unsigned*)(smem + 122880);
    float* red     = (float*)(smem + 122880);
    float* mb      = (float*)(smem + 122880);
    float* Bbn_s   = (float*)(smem + 155648);
    float* qn4s    = Bbn_s + 12;
    float* mrun_s  = qn4s + 192;
    float* lrun_s  = mrun_s + 96;
    float* coS_s   = lrun_s + 96;
    float* cwS_s   = coS_s + 96;

    const int tid = threadIdx.x;
    const int lane = tid & 63;
    const int w = tid >> 6;
    const int rowL = lane & 15;
    const int g = lane >> 4;
    const int r7 = rowL & 7;
    const int km = w >> 2, wd = w & 3;
    const int b = blockIdx.y;
    const int n0 = blockIdx.x * 16;
    const int obase = blockIdx.z * 6;
    const float scale = scale_p[0], riem_scale = riem_p[0], grass_scale = grass_p[0];

    if (tid < 432) {
        int o = tid / 36;
        float inv = bn_gamma[o] * rsqrtf(bn_var[o] + 1e-5f);
        cwS_s[tid] = cw[tid] * inv;
    }
    if (tid >= 448 && tid < 460) {
        int o = tid - 448;
        float inv = bn_gamma[o] * rsqrtf(bn_var[o] + 1e-5f);
        Bbn_s[o] = fmaf(conv_b[o] - bn_mean[o], inv, bn_beta[o]);
    }
    if (tid < 96) { mrun_s[tid] = -1e30f; lrun_s[tid] = 0.f; }
    if (tid < 192) qn4s[tid] = qn4g[(size_t)(b * 12 + (tid >> 4)) * 1024 + n0 + (tid & 15)];
#pragma unroll
    for (int e = 0; e < 6; e++) {
        int ci = tid + 512 * e;
        int R = ci >> 4, c = ci & 15;
        const unsigned* gp = qpk + ((size_t)(b * 12 + (R >> 4)) << 16) + (size_t)(n0 + (R & 15)) * 64 + c * 4;
        uint4 v = *(const uint4*)gp;
        *(uint4*)&qs[R * 64 + ((c ^ (R & 7)) << 2)] = v;
    }
#pragma unroll
    for (int e = 0; e < 3; e++) {
        int ci = tid + 512 * e;
        int R = ci >> 3, c = ci & 7;
        const unsigned short* gp = qgrh + ((size_t)(b * 12 + (R >> 4)) << 16) + (size_t)(n0 + (R & 15)) * 64 + c * 8;
        uint4 v = *(const uint4*)gp;
        *(uint4*)&qgs[R * 64 + ((c ^ (R & 7)) << 3)] = v;
    }

    EACH_O6(DECL_Y)
    EACH_O6(DECL_A)
    uint4 kreg[4], kgreg[2];

    for (int m0 = 0; m0 < 1024; m0 += 128) {
        for (int h = 0; h < 12; h++) {
            if (h == 0) {
                const unsigned* kp = kpk + ((size_t)(b * 12) << 16) + (size_t)m0 * 64;
                const unsigned short* kg = kgrh + ((size_t)(b * 12) << 16) + (size_t)m0 * 64;
#pragma unroll
                for (int e = 0; e < 4; e++) { int ci = tid + 512 * e; kreg[e] = *(const uint4*)&kp[(size_t)(ci >> 4) * 64 + (ci & 15) * 4]; }
#pragma unroll
                for (int e = 0; e < 2; e++) { int ci = tid + 512 * e; kgreg[e] = *(const uint4*)&kg[(size_t)(ci >> 3) * 64 + (ci & 7) * 8]; }
            }
#pragma unroll
            for (int e = 0; e < 4; e++) {
                int ci = tid + 512 * e; int m = ci >> 4, c = ci & 15;
                *(uint4*)&kL[m * 64 + ((c ^ (m & 7)) << 2)] = kreg[e];
            }
#pragma unroll
            for (int e = 0; e < 2; e++) {
                int ci = tid + 512 * e; int m = ci >> 3, c = ci & 7;
                *(uint4*)&kgrL[m * 64 + ((c ^ (m & 7)) << 3)] = kgreg[e];
            }
            if (h < 11) {
                const unsigned* kp = kpk + ((size_t)(b * 12 + h + 1) << 16) + (size_t)m0 * 64;
                const unsigned short* kg = kgrh + ((size_t)(b * 12 + h + 1) << 16) + (size_t)m0 * 64;
#pragma unroll
                for (int e = 0; e < 4; e++) { int ci = tid + 512 * e; kreg[e] = *(const uint4*)&kp[(size_t)(ci >> 4) * 64 + (ci & 15) * 4]; }
#pragma unroll
                for (int e = 0; e < 2; e++) { int ci = tid + 512 * e; kgreg[e] = *(const uint4*)&kg[(size_t)(ci >> 3) * 64 + (ci & 7) * 8]; }
            }
            __syncthreads();

            float kn4v = kn4g[(size_t)(b * 12 + h) * 1024 + m0 + w * 16 + rowL];
            f32x4 s1 = {0,0,0,0}, s2 = {0,0,0,0};
#pragma unroll
            for (int ks = 0; ks < 2; ks++) {
                int c0 = ks * 8 + g * 2;
                const unsigned* qrow = &qs[(h * 16 + rowL) * 64];
                uint4 a0 = *(const uint4*)&qrow[((c0 ^ r7) << 2)];
                uint4 a1 = *(const uint4*)&qrow[(((c0 + 1) ^ r7) << 2)];
                const unsigned* krow = &kL[(w * 16 + rowL) * 64];
                uint4 b0 = *(const uint4*)&krow[((c0 ^ r7) << 2)];
                uint4 b1 = *(const uint4*)&krow[(((c0 + 1) ^ r7) << 2)];
                short8 qhi = mk_hi(a0, a1), qlo = mk_lo(a0, a1);
                short8 khi = mk_hi(b0, b1), klo = mk_lo(b0, b1);
                s1 = MFMA(qhi, khi, s1);
                s1 = MFMA(qhi, klo, s1);
                s1 = MFMA(qlo, khi, s1);
                int cg = ks * 4 + g;
                short8 qg = *(const short8*)&qgs[(h * 16 + rowL) * 64 + ((cg ^ r7) << 3)];
                short8 kg2 = *(const short8*)&kgrL[(w * 16 + rowL) * 64 + ((cg ^ r7) << 3)];
                s2 = MFMA(qg, kg2, s2);
            }
            EACH_O6(LOADC)
            SCORE_R(0) SCORE_R(1) SCORE_R(2) SCORE_R(3)
            __syncthreads();
        }

        EACH_O6(SM1o)
        __syncthreads();
        if (tid < 96) {
            float m8 = red[tid * 8];
#pragma unroll
            for (int j = 1; j < 8; j++) m8 = fmaxf(m8, red[tid * 8 + j]);
            float mo = mrun_s[tid];
            float mn = fmaxf(mo, m8);
            mrun_s[tid] = mn;
            coS_s[tid] = expf(mo - mn);
        }
        __syncthreads();
        {
            int m_ = w * 16 + rowL;
            EACH_O6(SM2o)
        }
        __syncthreads();
        if (tid < 96) {
            float s8 = 0.f;
#pragma unroll
            for (int j = 0; j < 8; j++) s8 += red[tid * 8 + j];
            lrun_s[tid] = fmaf(lrun_s[tid], coS_s[tid], s8);
        }
        __syncthreads();

        EACH_O6(PVSTEP)
    }
    EACH_O6(EPI)
}

// ---------------- K4: out = attno @ proj_w^T + proj_b ----------------
__global__ __launch_bounds__(256) void proj_gemm(
    const float* __restrict__ x, const float* __restrict__ w, const float* __restrict__ bias,
    float* __restrict__ out)
{
    __shared__ float As[16][68];
    __shared__ float Ws[16][68];
    const int tid = threadIdx.x;
    const int m0 = blockIdx.x * 64;
    const int c0 = blockIdx.y * 64;
    const int ty = tid >> 4, tx = tid & 15;
    const int lm = tid >> 2;
    const int lk = (tid & 3) * 4;
    float acc[4][4];
#pragma unroll
    for (int i = 0; i < 4; i++)
#pragma unroll
        for (int j = 0; j < 4; j++) acc[i][j] = 0.f;

    for (int kk0 = 0; kk0 < 768; kk0 += 16) {
        float4 av = *(const float4*)&x[(m0 + lm) * 768 + kk0 + lk];
        float4 wv = *(const float4*)&w[(c0 + lm) * 768 + kk0 + lk];
        __syncthreads();
        As[lk + 0][lm] = av.x; As[lk + 1][lm] = av.y; As[lk + 2][lm] = av.z; As[lk + 3][lm] = av.w;
        Ws[lk + 0][lm] = wv.x; Ws[lk + 1][lm] = wv.y; Ws[lk + 2][lm] = wv.z; Ws[lk + 3][lm] = wv.w;
        __syncthreads();
#pragma unroll
        for (int kk = 0; kk < 16; kk++) {
            float4 a  = *(const float4*)&As[kk][ty * 4];
            float4 bv = *(const float4*)&Ws[kk][tx * 4];
            acc[0][0] += a.x * bv.x; acc[0][1] += a.x * bv.y; acc[0][2] += a.x * bv.z; acc[0][3] += a.x * bv.w;
            acc[1][0] += a.y * bv.x; acc[1][1] += a.y * bv.y; acc[1][2] += a.y * bv.z; acc[1][3] += a.y * bv.w;
            acc[2][0] += a.z * bv.x; acc[2][1] += a.z * bv.y; acc[2][2] += a.z * bv.z; acc[2][3] += a.z * bv.w;
            acc[3][0] += a.w * bv.x; acc[3][1] += a.w * bv.y; acc[3][2] += a.w * bv.z; acc[3][3] += a.w * bv.w;
        }
    }
#pragma unroll
    for (int i = 0; i < 4; i++) {
        int row = m0 + ty * 4 + i;
#pragma unroll
        for (int j = 0; j < 4; j++) {
            int col = c0 + tx * 4 + j;
            out[(size_t)row * 768 + col] = acc[i][j] + bias[col];
        }
    }
}

extern "C" void kernel_launch(void* const* d_in, const int* in_sizes, int n_in,
                              void* d_out, int out_size, void* d_ws, size_t ws_size,
                              hipStream_t stream) {
    const float* x          = (const float*)d_in[0];
    const float* qkv_w      = (const float*)d_in[1];
    const float* qkv_b      = (const float*)d_in[2];
    const float* proj_w     = (const float*)d_in[3];
    const float* proj_b     = (const float*)d_in[4];
    const float* scale      = (const float*)d_in[5];
    const float* riem_scale = (const float*)d_in[6];
    const float* grass_scale= (const float*)d_in[7];
    const float* conv_w     = (const float*)d_in[8];
    const float* conv_b     = (const float*)d_in[9];
    const float* bn_gamma   = (const float*)d_in[10];
    const float* bn_beta    = (const float*)d_in[11];
    const float* bn_mean    = (const float*)d_in[12];
    const float* bn_var     = (const float*)d_in[13];
    float* out = (float*)d_out;

    float* q   = (float*)d_ws;
    float* k   = q + 3145728;
    unsigned* qpk = (unsigned*)(k + 3145728);
    unsigned* kpk = qpk + 3145728;
    unsigned* vpk = kpk + 3145728;
    unsigned short* qgrh = (unsigned short*)(vpk + 3145728);
    unsigned short* kgrh = qgrh + 3145728;
    float* qn4 = (float*)(kgrh + 3145728);
    float* kn4 = qn4 + 49152;
    float* attno = q; // alias: q f32 dead after qr_kernel/row_norms

    const size_t BASE = 75890688ull;            // bytes used above
    const size_t SB1  = 50331648ull;            // one batch of S~ (12*1024*1024*4)
    float* Sbuf = (float*)((char*)d_ws + BASE);

    hipLaunchKernelGGL(qkv_gemm, dim3(64, 36), dim3(256), 0, stream,
                       x, qkv_w, qkv_b, q, k, qpk, kpk, vpk);
    hipLaunchKernelGGL(row_norms, dim3(24576), dim3(256), 0, stream, q, k, qn4, kn4);
    hipLaunchKernelGGL(qr_kernel, dim3(96), dim3(1024), 0, stream, q, k, qgrh, kgrh);

    if (ws_size >= BASE + 4 * SB1) {
        hipLaunchKernelGGL(sattn_scores, dim3(16, 128, 4), dim3(256), 0, stream,
                           qpk, kpk, qgrh, kgrh, qn4, kn4, conv_w, conv_b,
                           bn_gamma, bn_beta, bn_mean, bn_var,
                           scale, riem_scale, grass_scale, Sbuf, 0);
        hipLaunchKernelGGL(sattn_pv, dim3(64, 12, 4), dim3(256), 0, stream,
                           vpk, Sbuf, attno, 0);
    } else if (ws_size >= BASE + SB1) {
        for (int b = 0; b < 4; b++) {
            hipLaunchKernelGGL(sattn_scores, dim3(16, 128, 1), dim3(256), 0, stream,
                               qpk, kpk, qgrh, kgrh, qn4, kn4, conv_w, conv_b,
                               bn_gamma, bn_beta, bn_mean, bn_var,
                               scale, riem_scale, grass_scale, Sbuf, b);
            hipLaunchKernelGGL(sattn_pv, dim3(64, 12, 1), dim3(256), 0, stream,
                               vpk, Sbuf, attno, b);
        }
    } else {
        hipFuncSetAttribute(reinterpret_cast<const void*>(attn_fused),
                            hipFuncAttributeMaxDynamicSharedMemorySize, SM_BYTES);
        hipLaunchKernelGGL(attn_fused, dim3(64, 4, 2), dim3(512), SM_BYTES, stream,
                           qpk, kpk, vpk, qgrh, kgrh, qn4, kn4, conv_w, conv_b,
                           bn_gamma, bn_beta, bn_mean, bn_var,
                           scale, riem_scale, grass_scale, attno);
    }

    hipLaunchKernelGGL(proj_gemm, dim3(64, 12), dim3(256), 0, stream,
                       attno, proj_w, proj_b, out);
}

// Round 9
// 861.238 us; speedup vs baseline: 2.1055x; 1.1913x over previous
//
#include <hip/hip_runtime.h>
#include <math.h>

// B=4, N=1024, C=768, H=12, D=64
// ws: q[12.58MB] k qpk kpk vpk qgrh kgrh qn4 kn4  (= 75,890,688 B base)
// + V scratch (25.2MB, qr-internal, overlaps Sbuf) + S~ logits buffer (f32).

typedef __attribute__((ext_vector_type(8))) short short8;
typedef __attribute__((ext_vector_type(4))) float f32x4;

__device__ __forceinline__ unsigned bf16r(float x) {
    unsigned u = __float_as_uint(x);
    return (u + 0x7FFFu + ((u >> 16) & 1u)) >> 16;
}
__device__ __forceinline__ unsigned packhl(float x) {
    unsigned u = __float_as_uint(x);
    unsigned hi = (u + 0x7FFFu + ((u >> 16) & 1u)) & 0xFFFF0000u;
    float lo = x - __uint_as_float(hi);
    unsigned ul = __float_as_uint(lo);
    unsigned l16 = (ul + 0x7FFFu + ((ul >> 16) & 1u)) >> 16;
    return hi | (l16 & 0xFFFFu);
}
union U4S8 { uint4 u; short8 s; };
__device__ __forceinline__ short8 mk_hi(uint4 a, uint4 b) {
    U4S8 r;
    r.u.x = __builtin_amdgcn_perm(a.y, a.x, 0x07060302);
    r.u.y = __builtin_amdgcn_perm(a.w, a.z, 0x07060302);
    r.u.z = __builtin_amdgcn_perm(b.y, b.x, 0x07060302);
    r.u.w = __builtin_amdgcn_perm(b.w, b.z, 0x07060302);
    return r.s;
}
__device__ __forceinline__ short8 mk_lo(uint4 a, uint4 b) {
    U4S8 r;
    r.u.x = __builtin_amdgcn_perm(a.y, a.x, 0x05040100);
    r.u.y = __builtin_amdgcn_perm(a.w, a.z, 0x05040100);
    r.u.z = __builtin_amdgcn_perm(b.y, b.x, 0x05040100);
    r.u.w = __builtin_amdgcn_perm(b.w, b.z, 0x05040100);
    return r.s;
}
__device__ __forceinline__ uint4 ld4v(const unsigned* vp, int mbase, int d) {
    uint4 r;
    r.x = vp[(size_t)(mbase + 0) * 64 + d];
    r.y = vp[(size_t)(mbase + 1) * 64 + d];
    r.z = vp[(size_t)(mbase + 2) * 64 + d];
    r.w = vp[(size_t)(mbase + 3) * 64 + d];
    return r;
}
#define MFMA(a,b,c) __builtin_amdgcn_mfma_f32_16x16x32_bf16(a, b, c, 0, 0, 0)

// ---------------- K1: qkv GEMM + scatter (f32 + packed hi/lo bf16) ----------------
__global__ __launch_bounds__(256) void qkv_gemm(
    const float* __restrict__ x, const float* __restrict__ w, const float* __restrict__ bias,
    float* __restrict__ q, float* __restrict__ k,
    unsigned* __restrict__ qpk, unsigned* __restrict__ kpk, unsigned* __restrict__ vpk)
{
    __shared__ float As[16][68];
    __shared__ float Ws[16][68];
    const int tid = threadIdx.x;
    const int m0 = blockIdx.x * 64;
    const int c0 = blockIdx.y * 64;
    const int ty = tid >> 4, tx = tid & 15;
    const int lm = tid >> 2;
    const int lk = (tid & 3) * 4;
    float acc[4][4];
#pragma unroll
    for (int i = 0; i < 4; i++)
#pragma unroll
        for (int j = 0; j < 4; j++) acc[i][j] = 0.f;

    for (int kk0 = 0; kk0 < 768; kk0 += 16) {
        float4 av = *(const float4*)&x[(m0 + lm) * 768 + kk0 + lk];
        float4 wv = *(const float4*)&w[(c0 + lm) * 768 + kk0 + lk];
        __syncthreads();
        As[lk + 0][lm] = av.x; As[lk + 1][lm] = av.y; As[lk + 2][lm] = av.z; As[lk + 3][lm] = av.w;
        Ws[lk + 0][lm] = wv.x; Ws[lk + 1][lm] = wv.y; Ws[lk + 2][lm] = wv.z; Ws[lk + 3][lm] = wv.w;
        __syncthreads();
#pragma unroll
        for (int kk = 0; kk < 16; kk++) {
            float4 a  = *(const float4*)&As[kk][ty * 4];
            float4 bv = *(const float4*)&Ws[kk][tx * 4];
            acc[0][0] += a.x * bv.x; acc[0][1] += a.x * bv.y; acc[0][2] += a.x * bv.z; acc[0][3] += a.x * bv.w;
            acc[1][0] += a.y * bv.x; acc[1][1] += a.y * bv.y; acc[1][2] += a.y * bv.z; acc[1][3] += a.y * bv.w;
            acc[2][0] += a.z * bv.x; acc[2][1] += a.z * bv.y; acc[2][2] += a.z * bv.z; acc[2][3] += a.z * bv.w;
            acc[3][0] += a.w * bv.x; acc[3][1] += a.w * bv.y; acc[3][2] += a.w * bv.z; acc[3][3] += a.w * bv.w;
        }
    }
#pragma unroll
    for (int i = 0; i < 4; i++) {
        int row = m0 + ty * 4 + i;
        int bb = row >> 10, n = row & 1023;
#pragma unroll
        for (int j = 0; j < 4; j++) {
            int col = c0 + tx * 4 + j;
            float val = acc[i][j] + bias[col];
            int s = (col >= 1536) ? 2 : ((col >= 768) ? 1 : 0);
            int hc = col - s * 768;
            size_t idx = ((size_t)(bb * 12 + (hc >> 6)) << 16) + ((size_t)n << 6) + (hc & 63);
            if (s == 0)      { q[idx] = val; qpk[idx] = packhl(val); }
            else if (s == 1) { k[idx] = val; kpk[idx] = packhl(val); }
            else             { vpk[idx] = packhl(val); }
        }
    }
}

// ---------------- K1b: squared row norms ----------------
__global__ __launch_bounds__(256) void row_norms(
    const float* __restrict__ q, const float* __restrict__ k,
    float* __restrict__ qn4, float* __restrict__ kn4)
{
    int wid = blockIdx.x * 4 + (threadIdx.x >> 6);
    int lane = threadIdx.x & 63;
    const float* src; float* dst; int r;
    if (wid < 49152) { src = q; dst = qn4; r = wid; }
    else             { src = k; dst = kn4; r = wid - 49152; }
    float xv = src[(size_t)r * 64 + lane];
    float s = xv * xv;
#pragma unroll
    for (int m = 1; m < 64; m <<= 1) s += __shfl_xor(s, m, 64);
    if (lane == 0) dst[r] = s * s;
}

// ---------------- K2: Householder QR (LAPACK signs), bf16 output ----------------
// 1 barrier/step (double-buffered v), 4-wide interleaved butterflies,
// V streamed to global scratch so phase-2 holds only qr[] (no spill).
__global__ __launch_bounds__(1024, 4) void qr_kernel(
    const float* __restrict__ q, const float* __restrict__ k,
    unsigned short* __restrict__ qgrh, unsigned short* __restrict__ kgrh,
    float* __restrict__ Vg)
{
    const int id = blockIdx.x;
    const float* src = (id & 1) ? k : q;
    unsigned short* dst = (id & 1) ? kgrh : qgrh;
    const int bh = id >> 1;
    src += (size_t)bh << 16;
    dst += (size_t)bh << 16;
    float* Vm = Vg + (size_t)id * 65536;   // [64][1024]
    const int tid = threadIdx.x;
    const int lane = tid & 63;
    const int w = tid >> 6;
    __shared__ float vbufA[1024];
    __shared__ float vbufB[1024];
    __shared__ float taub[64];

    // ---------- phase 1: factorization ----------
    {
        float a[4][16];
#pragma unroll
        for (int c = 0; c < 4; c++)
#pragma unroll
            for (int i = 0; i < 16; i++)
                a[c][i] = src[(i * 64 + lane) * 64 + 4 * w + c];

        // owner precompute for d = 0 (wave 0, col 0)
        if (w == 0) {
            float part = 0.f;
#pragma unroll
            for (int i = 0; i < 16; i++) part += a[0][i] * a[0][i];
#pragma unroll
            for (int m = 1; m < 64; m <<= 1) part += __shfl_xor(part, m, 64);
            float sigma = part;
            float xd = __shfl(a[0][0], 0, 64);
            float nrm = sqrtf(sigma);
            float beta = (xd >= 0.f) ? -nrm : nrm;
            float vd = xd - beta;
            float vtv = (sigma - xd * xd) + vd * vd;
            float tau2 = (vtv > 0.f) ? 2.f / vtv : 0.f;
            if (lane == 0) a[0][0] = vd;
#pragma unroll
            for (int i = 0; i < 16; i++) {
                float vv = a[0][i];
                vbufA[i * 64 + lane] = vv;
                Vm[i * 64 + lane] = vv;
            }
            if (lane == 0) taub[0] = tau2;
        }
        __syncthreads();

        for (int d = 0; d < 64; d++) {
            float* vb = (d & 1) ? vbufB : vbufA;
            float vr[16];
#pragma unroll
            for (int i = 0; i < 16; i++) vr[i] = vb[i * 64 + lane];
            float t2 = taub[d];
            float dp0 = 0.f, dp1 = 0.f, dp2 = 0.f, dp3 = 0.f;
#pragma unroll
            for (int i = 0; i < 16; i++) {
                dp0 += vr[i] * a[0][i];
                dp1 += vr[i] * a[1][i];
                dp2 += vr[i] * a[2][i];
                dp3 += vr[i] * a[3][i];
            }
#pragma unroll
            for (int m = 1; m < 64; m <<= 1) {
                dp0 += __shfl_xor(dp0, m, 64);
                dp1 += __shfl_xor(dp1, m, 64);
                dp2 += __shfl_xor(dp2, m, 64);
                dp3 += __shfl_xor(dp3, m, 64);
            }
            const int jb = 4 * w;
            float s0 = t2 * dp0, s1 = t2 * dp1, s2 = t2 * dp2, s3 = t2 * dp3;
            if (jb + 0 > d) {
#pragma unroll
                for (int i = 0; i < 16; i++) a[0][i] -= s0 * vr[i];
            }
            if (jb + 1 > d) {
#pragma unroll
                for (int i = 0; i < 16; i++) a[1][i] -= s1 * vr[i];
            }
            if (jb + 2 > d) {
#pragma unroll
                for (int i = 0; i < 16; i++) a[2][i] -= s2 * vr[i];
            }
            if (jb + 3 > d) {
#pragma unroll
                for (int i = 0; i < 16; i++) a[3][i] -= s3 * vr[i];
            }
            if (d < 63) {
                const int dn = d + 1;
                if (w == (dn >> 2)) {
                    const int cd = dn & 3;
#pragma unroll
                    for (int c = 0; c < 4; c++) if (c == cd) {
                        float part = 0.f;
#pragma unroll
                        for (int i = 0; i < 16; i++) {
                            int r = i * 64 + lane;
                            float xx = a[c][i];
                            part += (r >= dn) ? xx * xx : 0.f;
                        }
#pragma unroll
                        for (int m = 1; m < 64; m <<= 1) part += __shfl_xor(part, m, 64);
                        float sigma = part;
                        float xd = __shfl(a[c][0], dn, 64);
                        float nrm = sqrtf(sigma);
                        float beta = (xd >= 0.f) ? -nrm : nrm;
                        float vd = xd - beta;
                        float vtv = (sigma - xd * xd) + vd * vd;
                        float tau2 = (vtv > 0.f) ? 2.f / vtv : 0.f;
                        if (lane == dn) a[c][0] = vd;
                        float* vbn = (dn & 1) ? vbufB : vbufA;
#pragma unroll
                        for (int i = 0; i < 16; i++) {
                            int r = i * 64 + lane;
                            float vv = (r < dn) ? 0.f : a[c][i];
                            vbn[i * 64 + lane] = vv;
                            Vm[(size_t)dn * 1024 + i * 64 + lane] = vv;
                        }
                        if (lane == 0) taub[dn] = tau2;
                    }
                }
            }
            __syncthreads();
        }
    } // a[] dead here — V lives in Vm

    // ---------- phase 2: Q = H0..H63 [I;0], stream V from global ----------
    float qr[4][16];
#pragma unroll
    for (int c = 0; c < 4; c++)
#pragma unroll
        for (int i = 0; i < 16; i++) {
            int r = i * 64 + lane;
            qr[c][i] = (r == 4 * w + c) ? 1.f : 0.f;
        }
    // preload v_63 into buffer parity 1
    vbufB[tid] = Vm[(size_t)63 * 1024 + tid];
    __syncthreads();
    for (int d = 63; d >= 0; d--) {
        float* vb = (d & 1) ? vbufB : vbufA;
        float nv = 0.f;
        if (d > 0) nv = Vm[(size_t)(d - 1) * 1024 + tid];   // prefetch next v
        float vr[16];
#pragma unroll
        for (int i = 0; i < 16; i++) vr[i] = vb[i * 64 + lane];
        float t2 = taub[d];
        float dp0 = 0.f, dp1 = 0.f, dp2 = 0.f, dp3 = 0.f;
#pragma unroll
        for (int i = 0; i < 16; i++) {
            dp0 += vr[i] * qr[0][i];
            dp1 += vr[i] * qr[1][i];
            dp2 += vr[i] * qr[2][i];
            dp3 += vr[i] * qr[3][i];
        }
#pragma unroll
        for (int m = 1; m < 64; m <<= 1) {
            dp0 += __shfl_xor(dp0, m, 64);
            dp1 += __shfl_xor(dp1, m, 64);
            dp2 += __shfl_xor(dp2, m, 64);
            dp3 += __shfl_xor(dp3, m, 64);
        }
        const int jb = 4 * w;
        float s0 = t2 * dp0, s1 = t2 * dp1, s2 = t2 * dp2, s3 = t2 * dp3;
        if (jb + 0 >= d) {
#pragma unroll
            for (int i = 0; i < 16; i++) qr[0][i] -= s0 * vr[i];
        }
        if (jb + 1 >= d) {
#pragma unroll
            for (int i = 0; i < 16; i++) qr[1][i] -= s1 * vr[i];
        }
        if (jb + 2 >= d) {
#pragma unroll
            for (int i = 0; i < 16; i++) qr[2][i] -= s2 * vr[i];
        }
        if (jb + 3 >= d) {
#pragma unroll
            for (int i = 0; i < 16; i++) qr[3][i] -= s3 * vr[i];
        }
        if (d > 0) {
            float* vbn = ((d - 1) & 1) ? vbufB : vbufA;
            vbn[tid] = nv;
        }
        __syncthreads();
    }
#pragma unroll
    for (int c = 0; c < 4; c++)
#pragma unroll
        for (int i = 0; i < 16; i++)
            dst[(i * 64 + lane) * 64 + 4 * w + c] = (unsigned short)bf16r(qr[c][i]);
}

// ================= SPLIT PATH =================
#define SC_EACH(F) F(0) F(1) F(2) F(3) F(4) F(5)
#define SC_DECLY(o) float y##o##_0 = 0.f, y##o##_1 = 0.f, y##o##_2 = 0.f, y##o##_3 = 0.f;
#define SC_LOADC(o) const float cA##o = cw[(obase + o) * 36 + h], \
                                cB##o = cw[(obase + o) * 36 + 12 + h], \
                                cC##o = cw[(obase + o) * 36 + 24 + h];
#define SC_CONV1(o,r) y##o##_##r = fmaf(cA##o, att, fmaf(cB##o, rie, fmaf(cC##o, gra, y##o##_##r)));
#define SC_CONVROW(r) SC_CONV1(0,r) SC_CONV1(1,r) SC_CONV1(2,r) SC_CONV1(3,r) SC_CONV1(4,r) SC_CONV1(5,r)
#define SC_SCORE(r) { \
    float qk = s1[r], gr = s2[r]; \
    float qn4v = qn4s[g * 4 + r]; \
    float att = qk * scale; \
    float d2 = qn4v + kn4v - 2.f * qk * qk; \
    float rie = -sqrtf(fmaxf(d2, 0.f) + 1e-8f) * riem_scale; \
    float gra = gr * gr * grass_scale; \
    SC_CONVROW(r) }
#define SC_OUT(o) { \
    float inv = bn_gamma[obase + o] * rsqrtf(bn_var[obase + o] + 1e-5f); \
    float Bb = fmaf(conv_b[obase + o] - bn_mean[obase + o], inv, bn_beta[obase + o]); \
    float* dst = Sbuf + ((size_t)(z * 12 + obase + o) * 1024 + n0) * 1024 + m0 + w * 16 + rowL; \
    dst[(size_t)(g * 4 + 0) * 1024] = fmaf(y##o##_0, inv, Bb); \
    dst[(size_t)(g * 4 + 1) * 1024] = fmaf(y##o##_1, inv, Bb); \
    dst[(size_t)(g * 4 + 2) * 1024] = fmaf(y##o##_2, inv, Bb); \
    dst[(size_t)(g * 4 + 3) * 1024] = fmaf(y##o##_3, inv, Bb); }

__global__ __launch_bounds__(256) void sattn_scores(
    const unsigned* __restrict__ qpk, const unsigned* __restrict__ kpk,
    const unsigned short* __restrict__ qgrh, const unsigned short* __restrict__ kgrh,
    const float* __restrict__ qn4g, const float* __restrict__ kn4g,
    const float* __restrict__ cw, const float* __restrict__ conv_b,
    const float* __restrict__ bn_gamma, const float* __restrict__ bn_beta,
    const float* __restrict__ bn_mean, const float* __restrict__ bn_var,
    const float* __restrict__ scale_p, const float* __restrict__ riem_p,
    const float* __restrict__ grass_p, float* __restrict__ Sbuf, int b0)
{
    __shared__ unsigned qT[16 * 64];
    __shared__ unsigned short qgT[16 * 64];
    __shared__ unsigned kL[64 * 64];
    __shared__ unsigned short kgrL[64 * 64];
    __shared__ float qn4s[16];
    __shared__ float kn4s[64];

    const int tid = threadIdx.x;
    const int lane = tid & 63;
    const int w = tid >> 6;
    const int rowL = lane & 15;
    const int g = lane >> 4;
    const int r7 = rowL & 7;
    const int m0 = blockIdx.x * 64;
    const int n0 = (blockIdx.y >> 1) * 16;
    const int obase = (blockIdx.y & 1) * 6;
    const int z = blockIdx.z;
    const int b = b0 + z;
    const float scale = scale_p[0], riem_scale = riem_p[0], grass_scale = grass_p[0];

    SC_EACH(SC_DECLY)

    for (int h = 0; h < 12; h++) {
        __syncthreads();
        {
            int R = tid >> 4, c = tid & 15;
            uint4 v = *(const uint4*)&qpk[((size_t)(b * 12 + h) << 16) + (size_t)(n0 + R) * 64 + c * 4];
            *(uint4*)&qT[R * 64 + ((c ^ (R & 7)) << 2)] = v;
        }
        if (tid < 128) {
            int R = tid >> 3, c = tid & 7;
            uint4 v = *(const uint4*)&qgrh[((size_t)(b * 12 + h) << 16) + (size_t)(n0 + R) * 64 + c * 8];
            *(uint4*)&qgT[R * 64 + ((c ^ (R & 7)) << 3)] = v;
        }
#pragma unroll
        for (int e = 0; e < 4; e++) {
            int ci = tid + 256 * e; int m = ci >> 4, c = ci & 15;
            uint4 v = *(const uint4*)&kpk[((size_t)(b * 12 + h) << 16) + (size_t)(m0 + m) * 64 + c * 4];
            *(uint4*)&kL[m * 64 + ((c ^ (m & 7)) << 2)] = v;
        }
#pragma unroll
        for (int e = 0; e < 2; e++) {
            int ci = tid + 256 * e; int m = ci >> 3, c = ci & 7;
            uint4 v = *(const uint4*)&kgrh[((size_t)(b * 12 + h) << 16) + (size_t)(m0 + m) * 64 + c * 8];
            *(uint4*)&kgrL[m * 64 + ((c ^ (m & 7)) << 3)] = v;
        }
        if (tid < 64) kn4s[tid] = kn4g[(size_t)(b * 12 + h) * 1024 + m0 + tid];
        if (tid < 16) qn4s[tid] = qn4g[(size_t)(b * 12 + h) * 1024 + n0 + tid];
        __syncthreads();

        float kn4v = kn4s[w * 16 + rowL];
        f32x4 s1 = {0,0,0,0}, s2 = {0,0,0,0};
#pragma unroll
        for (int ks = 0; ks < 2; ks++) {
            int c0 = ks * 8 + g * 2;
            uint4 a0 = *(const uint4*)&qT[rowL * 64 + ((c0 ^ r7) << 2)];
            uint4 a1 = *(const uint4*)&qT[rowL * 64 + (((c0 + 1) ^ r7) << 2)];
            uint4 b0v = *(const uint4*)&kL[(w * 16 + rowL) * 64 + ((c0 ^ r7) << 2)];
            uint4 b1v = *(const uint4*)&kL[(w * 16 + rowL) * 64 + (((c0 + 1) ^ r7) << 2)];
            short8 qhi = mk_hi(a0, a1), qlo = mk_lo(a0, a1);
            short8 khi = mk_hi(b0v, b1v), klo = mk_lo(b0v, b1v);
            s1 = MFMA(qhi, khi, s1);
            s1 = MFMA(qhi, klo, s1);
            s1 = MFMA(qlo, khi, s1);
            int cg = ks * 4 + g;
            short8 qg = *(const short8*)&qgT[rowL * 64 + ((cg ^ r7) << 3)];
            short8 kg2 = *(const short8*)&kgrL[(w * 16 + rowL) * 64 + ((cg ^ r7) << 3)];
            s2 = MFMA(qg, kg2, s2);
        }
        SC_EACH(SC_LOADC)
        SC_SCORE(0) SC_SCORE(1) SC_SCORE(2) SC_SCORE(3)
    }
    SC_EACH(SC_OUT)
}

__global__ __launch_bounds__(256) void sattn_pv(
    const unsigned* __restrict__ vpk, const float* __restrict__ Sbuf,
    float* __restrict__ attno, int b0)
{
    __shared__ unsigned short P_s[16 * 64];
    __shared__ unsigned vt_s[64 * 64];
    __shared__ float mrun[16], lrun[16], cos_[16];

    const int tid = threadIdx.x;
    const int lane = tid & 63;
    const int w = tid >> 6;
    const int rowL = lane & 15;
    const int g = lane >> 4;
    const int r7 = rowL & 7;
    const int n0 = blockIdx.x * 16;
    const int o = blockIdx.y;
    const int z = blockIdx.z;
    const int b = b0 + z;
    const int srow = tid >> 4;
    const int sc4 = (tid & 15) * 4;

    if (tid < 16) { mrun[tid] = -1e30f; lrun[tid] = 0.f; }
    f32x4 acc = {0,0,0,0};
    const float* Srow = Sbuf + ((size_t)(z * 12 + o) * 1024 + n0 + srow) * 1024;
    const unsigned* vp = vpk + ((size_t)(b * 12 + o) << 16);
    __syncthreads();

    for (int m0 = 0; m0 < 1024; m0 += 64) {
        float4 sv = *(const float4*)&Srow[m0 + sc4];
        float mx = fmaxf(fmaxf(sv.x, sv.y), fmaxf(sv.z, sv.w));
        mx = fmaxf(mx, __shfl_xor(mx, 1, 64));
        mx = fmaxf(mx, __shfl_xor(mx, 2, 64));
        mx = fmaxf(mx, __shfl_xor(mx, 4, 64));
        mx = fmaxf(mx, __shfl_xor(mx, 8, 64));
        float mo = mrun[srow];
        float mn = fmaxf(mo, mx);
        float co = expf(mo - mn);
        float p0 = expf(sv.x - mn), p1 = expf(sv.y - mn), p2 = expf(sv.z - mn), p3 = expf(sv.w - mn);
        unsigned u0 = bf16r(p0), u1 = bf16r(p1), u2 = bf16r(p2), u3 = bf16r(p3);
        {
            ushort4 pw = make_ushort4((unsigned short)u0, (unsigned short)u1,
                                      (unsigned short)u2, (unsigned short)u3);
            *(ushort4*)&P_s[srow * 64 + (((sc4 >> 3) ^ (srow & 7)) << 3) + (sc4 & 7)] = pw;
        }
        float ps = __uint_as_float(u0 << 16) + __uint_as_float(u1 << 16)
                 + __uint_as_float(u2 << 16) + __uint_as_float(u3 << 16);
        ps += __shfl_xor(ps, 1, 64); ps += __shfl_xor(ps, 2, 64);
        ps += __shfl_xor(ps, 4, 64); ps += __shfl_xor(ps, 8, 64);
        if ((lane & 15) == 0) {
            mrun[srow] = mn;
            cos_[srow] = co;
            lrun[srow] = lrun[srow] * co + ps;
        }
#pragma unroll
        for (int e = 0; e < 4; e++) {
            int d_ = tid & 63;
            int mb = (tid >> 6) * 4 + 16 * e;
            int mc = (tid >> 6) + 4 * e;
            uint4 v = ld4v(vp + (size_t)m0 * 64, mb, d_);
            *(uint4*)&vt_s[d_ * 64 + ((mc ^ (d_ & 15)) << 2)] = v;
        }
        __syncthreads();
        {
            float c0_ = cos_[g * 4 + 0], c1_ = cos_[g * 4 + 1];
            float c2_ = cos_[g * 4 + 2], c3_ = cos_[g * 4 + 3];
            acc[0] *= c0_; acc[1] *= c1_; acc[2] *= c2_; acc[3] *= c3_;
        }
        const int d_ = w * 16 + rowL;
        const unsigned* vrow = &vt_s[d_ * 64];
#pragma unroll
        for (int kk = 0; kk < 2; kk++) {
            int mc8 = kk * 4 + g;
            short8 pa = *(const short8*)&P_s[rowL * 64 + ((mc8 ^ r7) << 3)];
            int c0 = kk * 8 + g * 2;
            uint4 b0v = *(const uint4*)&vrow[((c0 ^ (d_ & 15)) << 2)];
            uint4 b1v = *(const uint4*)&vrow[(((c0 + 1) ^ (d_ & 15)) << 2)];
            short8 vh = mk_hi(b0v, b1v), vl = mk_lo(b0v, b1v);
            acc = MFMA(pa, vh, acc);
            acc = MFMA(pa, vl, acc);
        }
        __syncthreads();
    }
#pragma unroll
    for (int r = 0; r < 4; r++) {
        int row = g * 4 + r;
        attno[((size_t)(b * 1024 + n0 + row)) * 768 + o * 64 + w * 16 + rowL] = acc[r] / lrun[row];
    }
}

// ---------------- K4: out = attno @ proj_w^T + proj_b ----------------
__global__ __launch_bounds__(256) void proj_gemm(
    const float* __restrict__ x, const float* __restrict__ w, const float* __restrict__ bias,
    float* __restrict__ out)
{
    __shared__ float As[16][68];
    __shared__ float Ws[16][68];
    const int tid = threadIdx.x;
    const int m0 = blockIdx.x * 64;
    const int c0 = blockIdx.y * 64;
    const int ty = tid >> 4, tx = tid & 15;
    const int lm = tid >> 2;
    const int lk = (tid & 3) * 4;
    float acc[4][4];
#pragma unroll
    for (int i = 0; i < 4; i++)
#pragma unroll
        for (int j = 0; j < 4; j++) acc[i][j] = 0.f;

    for (int kk0 = 0; kk0 < 768; kk0 += 16) {
        float4 av = *(const float4*)&x[(m0 + lm) * 768 + kk0 + lk];
        float4 wv = *(const float4*)&w[(c0 + lm) * 768 + kk0 + lk];
        __syncthreads();
        As[lk + 0][lm] = av.x; As[lk + 1][lm] = av.y; As[lk + 2][lm] = av.z; As[lk + 3][lm] = av.w;
        Ws[lk + 0][lm] = wv.x; Ws[lk + 1][lm] = wv.y; Ws[lk + 2][lm] = wv.z; Ws[lk + 3][lm] = wv.w;
        __syncthreads();
#pragma unroll
        for (int kk = 0; kk < 16; kk++) {
            float4 a  = *(const float4*)&As[kk][ty * 4];
            float4 bv = *(const float4*)&Ws[kk][tx * 4];
            acc[0][0] += a.x * bv.x; acc[0][1] += a.x * bv.y; acc[0][2] += a.x * bv.z; acc[0][3] += a.x * bv.w;
            acc[1][0] += a.y * bv.x; acc[1][1] += a.y * bv.y; acc[1][2] += a.y * bv.z; acc[1][3] += a.y * bv.w;
            acc[2][0] += a.z * bv.x; acc[2][1] += a.z * bv.y; acc[2][2] += a.z * bv.z; acc[2][3] += a.z * bv.w;
            acc[3][0] += a.w * bv.x; acc[3][1] += a.w * bv.y; acc[3][2] += a.w * bv.z; acc[3][3] += a.w * bv.w;
        }
    }
#pragma unroll
    for (int i = 0; i < 4; i++) {
        int row = m0 + ty * 4 + i;
#pragma unroll
        for (int j = 0; j < 4; j++) {
            int col = c0 + tx * 4 + j;
            out[(size_t)row * 768 + col] = acc[i][j] + bias[col];
        }
    }
}

extern "C" void kernel_launch(void* const* d_in, const int* in_sizes, int n_in,
                              void* d_out, int out_size, void* d_ws, size_t ws_size,
                              hipStream_t stream) {
    const float* x          = (const float*)d_in[0];
    const float* qkv_w      = (const float*)d_in[1];
    const float* qkv_b      = (const float*)d_in[2];
    const float* proj_w     = (const float*)d_in[3];
    const float* proj_b     = (const float*)d_in[4];
    const float* scale      = (const float*)d_in[5];
    const float* riem_scale = (const float*)d_in[6];
    const float* grass_scale= (const float*)d_in[7];
    const float* conv_w     = (const float*)d_in[8];
    const float* conv_b     = (const float*)d_in[9];
    const float* bn_gamma   = (const float*)d_in[10];
    const float* bn_beta    = (const float*)d_in[11];
    const float* bn_mean    = (const float*)d_in[12];
    const float* bn_var     = (const float*)d_in[13];
    float* out = (float*)d_out;

    float* q   = (float*)d_ws;
    float* k   = q + 3145728;
    unsigned* qpk = (unsigned*)(k + 3145728);
    unsigned* kpk = qpk + 3145728;
    unsigned* vpk = kpk + 3145728;
    unsigned short* qgrh = (unsigned short*)(vpk + 3145728);
    unsigned short* kgrh = qgrh + 3145728;
    float* qn4 = (float*)(kgrh + 3145728);
    float* kn4 = qn4 + 49152;
    float* attno = q; // alias: q f32 dead after qr_kernel/row_norms

    const size_t BASE = 75890688ull;
    const size_t SB1  = 50331648ull;            // one batch of S~ (12*1024*1024*4)
    float* Sbuf = (float*)((char*)d_ws + BASE);
    float* Vg   = Sbuf;                          // qr V scratch (25.2MB), dead before Sbuf written

    hipLaunchKernelGGL(qkv_gemm, dim3(64, 36), dim3(256), 0, stream,
                       x, qkv_w, qkv_b, q, k, qpk, kpk, vpk);
    hipLaunchKernelGGL(row_norms, dim3(24576), dim3(256), 0, stream, q, k, qn4, kn4);
    hipLaunchKernelGGL(qr_kernel, dim3(96), dim3(1024), 0, stream, q, k, qgrh, kgrh, Vg);

    if (ws_size >= BASE + 4 * SB1) {
        hipLaunchKernelGGL(sattn_scores, dim3(16, 128, 4), dim3(256), 0, stream,
                           qpk, kpk, qgrh, kgrh, qn4, kn4, conv_w, conv_b,
                           bn_gamma, bn_beta, bn_mean, bn_var,
                           scale, riem_scale, grass_scale, Sbuf, 0);
        hipLaunchKernelGGL(sattn_pv, dim3(64, 12, 4), dim3(256), 0, stream,
                           vpk, Sbuf, attno, 0);
    } else {
        for (int b = 0; b < 4; b++) {
            hipLaunchKernelGGL(sattn_scores, dim3(16, 128, 1), dim3(256), 0, stream,
                               qpk, kpk, qgrh, kgrh, qn4, kn4, conv_w, conv_b,
                               bn_gamma, bn_beta, bn_mean, bn_var,
                               scale, riem_scale, grass_scale, Sbuf, b);
            hipLaunchKernelGGL(sattn_pv, dim3(64, 12, 1), dim3(256), 0, stream,
                               vpk, Sbuf, attno, b);
        }
    }

    hipLaunchKernelGGL(proj_gemm, dim3(64, 12), dim3(256), 0, stream,
                       attno, proj_w, proj_b, out);
}